// Round 13
// baseline (156.490 us; speedup 1.0000x reference)
//
#include <hip/hip_runtime.h>
#include <math.h>

#define D 64
#define SCAN_ELEMS 1024    // elements per scan block (256 thr x 4)
#define STEP 256           // nodes per partition bucket (key space 2N)
#define SHIFT 8            // log2(STEP)
#define PART_CHUNK 2048    // edges per partition WG

// Node ids fit u16 (N=50000 < 65536). Partition items: (local_key<<16)|other.
// X, h, W staged bf16. GEMM on MFMA. Gathers split by dim-half so each pass's
// table (3.2MB) fits a 4MB XCD L2 (R12 lesson: gathers were L2-thrash-bound,
// not BW/issue-bound).

typedef __attribute__((ext_vector_type(8))) short bf16x8;
typedef __attribute__((ext_vector_type(8))) unsigned short u16x8;
typedef __attribute__((ext_vector_type(4))) float f32x4;

__device__ inline unsigned short f2bf(float f) {   // round-to-nearest-even
    unsigned u = __float_as_uint(f);
    return (unsigned short)((u + 0x7FFFu + ((u >> 16) & 1u)) >> 16);
}
__device__ inline float bf2f(unsigned short h) {
    return __uint_as_float(((unsigned)h) << 16);
}

// ---------------------------------------------------------------------------
// to_bf16_all: convert X, Wn, Ws in one launch (block ranges)
// ---------------------------------------------------------------------------
__global__ __launch_bounds__(256) void to_bf16_all(
    const float* __restrict__ X, const float* __restrict__ Wn,
    const float* __restrict__ Ws, unsigned short* __restrict__ Xh,
    unsigned short* __restrict__ Whn, unsigned short* __restrict__ Whs,
    int n8x, int n8w) {
    int i = blockIdx.x * blockDim.x + threadIdx.x;
    const float* in; unsigned short* outh; int idx;
    if (i < n8x) { in = X; outh = Xh; idx = i; }
    else if (i < n8x + n8w) { in = Wn; outh = Whn; idx = i - n8x; }
    else if (i < n8x + 2 * n8w) { in = Ws; outh = Whs; idx = i - n8x - n8w; }
    else return;
    const float4* p = (const float4*)in + (size_t)idx * 2;
    float4 a = p[0], b = p[1];
    union { unsigned short us[8]; uint4 v; } u;
    u.us[0] = f2bf(a.x); u.us[1] = f2bf(a.y); u.us[2] = f2bf(a.z); u.us[3] = f2bf(a.w);
    u.us[4] = f2bf(b.x); u.us[5] = f2bf(b.y); u.us[6] = f2bf(b.z); u.us[7] = f2bf(b.w);
    ((uint4*)outh)[idx] = u.v;
}

// ---------------------------------------------------------------------------
// part_hist: per-WG histogram of items into K coarse buckets (LDS counters).
// ---------------------------------------------------------------------------
__global__ __launch_bounds__(256) void part_hist(
    const int* __restrict__ src, const int* __restrict__ dst,
    int* __restrict__ cnt, int nE, int nN, int K, int WGs) {
    __shared__ int lh[1024];
    int wg = blockIdx.x;
    for (int i = threadIdx.x; i < K; i += 256) lh[i] = 0;
    __syncthreads();
    int base = wg * PART_CHUNK;
    int lim = min(base + PART_CHUNK, nE);
    for (int e = base + threadIdx.x; e < lim; e += 256) {
        int s = src[e], t = dst[e];
        atomicAdd(&lh[t >> SHIFT], 1);
        atomicAdd(&lh[(nN + s) >> SHIFT], 1);
    }
    __syncthreads();
    for (int b = threadIdx.x; b < K; b += 256) cnt[b * WGs + wg] = lh[b];
}

// ---------------------------------------------------------------------------
// scan pass 1: per-block sums
// ---------------------------------------------------------------------------
__global__ __launch_bounds__(256) void scan_part(
    const int* __restrict__ in, int* __restrict__ bsum, int n) {
    __shared__ int sdata[256];
    int b = blockIdx.x, t = threadIdx.x;
    int base = b * SCAN_ELEMS + t * 4;
    int s = 0;
#pragma unroll
    for (int k = 0; k < 4; ++k) { int i = base + k; if (i < n) s += in[i]; }
    sdata[t] = s;
    __syncthreads();
    for (int o = 128; o > 0; o >>= 1) {
        if (t < o) sdata[t] += sdata[t + o];
        __syncthreads();
    }
    if (t == 0) bsum[b] = sdata[0];
}

// ---------------------------------------------------------------------------
// scan pass 2: exclusive scan of block sums in place (nb <= 256)
// ---------------------------------------------------------------------------
__global__ __launch_bounds__(256) void scan_tops(int* __restrict__ bsum, int nb) {
    __shared__ int sd[256];
    int t = threadIdx.x;
    int v = (t < nb) ? bsum[t] : 0;
    sd[t] = v;
    __syncthreads();
    for (int o = 1; o < 256; o <<= 1) {
        int u = (t >= o) ? sd[t - o] : 0;
        __syncthreads();
        sd[t] += u;
        __syncthreads();
    }
    if (t < nb) bsum[t] = sd[t] - v;   // exclusive
}

// ---------------------------------------------------------------------------
// scan pass 3: per-chunk exclusive scan + block offset -> out
// ---------------------------------------------------------------------------
__global__ __launch_bounds__(256) void scan_final(
    const int* __restrict__ in, const int* __restrict__ bsum,
    int* __restrict__ out, int n) {
    __shared__ int sth[256];
    int b = blockIdx.x, t = threadIdx.x;
    int base = b * SCAN_ELEMS + t * 4;
    int v[4]; int s = 0;
#pragma unroll
    for (int k = 0; k < 4; ++k) { int i = base + k; v[k] = (i < n) ? in[i] : 0; s += v[k]; }
    sth[t] = s;
    __syncthreads();
    for (int o = 1; o < 256; o <<= 1) {
        int u = (t >= o) ? sth[t - o] : 0;
        __syncthreads();
        sth[t] += u;
        __syncthreads();
    }
    int run = sth[t] - s + bsum[b];
#pragma unroll
    for (int k = 0; k < 4; ++k) {
        int i = base + k;
        if (i < n) { out[i] = run; run += v[k]; }
    }
}

// ---------------------------------------------------------------------------
// part_write: each WG writes items into ITS OWN contiguous slice of each
// bucket region. Single owner + temporally compact -> writeback ~= payload.
// ---------------------------------------------------------------------------
__global__ __launch_bounds__(256) void part_write(
    const int* __restrict__ src, const int* __restrict__ dst,
    const int* __restrict__ scanned, unsigned int* __restrict__ part,
    int nE, int nN, int K, int WGs) {
    __shared__ int cur[1024];
    int wg = blockIdx.x;
    for (int b = threadIdx.x; b < K; b += 256) cur[b] = scanned[b * WGs + wg];
    __syncthreads();
    int base = wg * PART_CHUNK;
    int lim = min(base + PART_CHUNK, nE);
    for (int e = base + threadIdx.x; e < lim; e += 256) {
        int s = src[e], t = dst[e];
        int k1 = t;
        int p1 = atomicAdd(&cur[k1 >> SHIFT], 1);
        part[p1] = ((unsigned)(k1 & (STEP - 1)) << 16) | (unsigned)s;
        int k2 = nN + s;
        int p2 = atomicAdd(&cur[k2 >> SHIFT], 1);
        part[p2] = ((unsigned)(k2 & (STEP - 1)) << 16) | (unsigned)t;
    }
}

// ---------------------------------------------------------------------------
// csr_build: one WG per bucket. LDS degree count + prefix -> off[] exact,
// then scatter u16 vals into the WG-private region.
// ---------------------------------------------------------------------------
__global__ __launch_bounds__(256) void csr_build(
    const unsigned int* __restrict__ part, const int* __restrict__ scanned,
    unsigned short* __restrict__ vals, int* __restrict__ off,
    int n2, int K, int WGs, int totalItems) {
    __shared__ int deg[STEP];
    __shared__ int pfx[STEP];
    int b = blockIdx.x, t = threadIdx.x;
    int base = scanned[b * WGs];
    int endi = (b + 1 < K) ? scanned[(b + 1) * WGs] : totalItems;

    deg[t] = 0;
    __syncthreads();
    for (int i = base + t; i < endi; i += 256)
        atomicAdd(&deg[part[i] >> 16], 1);
    __syncthreads();

    pfx[t] = deg[t];
    __syncthreads();
    for (int o = 1; o < STEP; o <<= 1) {
        int u = (t >= o) ? pfx[t - o] : 0;
        __syncthreads();
        pfx[t] += u;
        __syncthreads();
    }
    int ex = pfx[t] - deg[t];
    int g = b * STEP + t;
    if (g < n2) off[g] = base + ex;
    if (b == K - 1 && t == 0) off[n2] = totalItems;
    deg[t] = ex;           // reuse as bucket-local cursor
    __syncthreads();

    for (int i = base + t; i < endi; i += 256) {
        unsigned u = part[i];
        int l = (int)(u >> 16);
        int p = atomicAdd(&deg[l], 1);
        vals[base + p] = (unsigned short)(u & 0xffffu);
    }
}

// ---------------------------------------------------------------------------
// agg_mean_half: per node wave, gather HALF-rows (64B) of Xh over incoming
// edges. 16 groups x 4 lanes x ushort8 = 16 rows / 1KB per instr, 32 rows
// in flight. Mean -> Am[n][half*32..+31] (bf16). Table footprint/pass =
// 3.2MB -> XCD-L2 resident (the whole point).
// ---------------------------------------------------------------------------
__global__ __launch_bounds__(256) void agg_mean_half(
    const unsigned short* __restrict__ Xh,    // [N*D] bf16
    const int* __restrict__ off,              // [2N+1]
    const unsigned short* __restrict__ vals,  // [2E]
    unsigned short* __restrict__ Am,          // [N*D] bf16 (means)
    int nNodes, int half) {
    int t = threadIdx.x;
    int li = t >> 6;
    int lane = t & 63;
    int g = lane >> 2;     // edge group 0..15
    int q = lane & 3;      // ushort8 chunk: half dims 8q..8q+7
    int node = blockIdx.x * 4 + li;
    if (node >= nNodes) return;

    const unsigned short* tab = Xh + half * 32 + 8 * q;
    int beg = off[node], end = off[node + 1];

    float acc[8];
#pragma unroll
    for (int j = 0; j < 8; ++j) acc[j] = 0.f;

    int base = beg;
    for (; base + 32 <= end; base += 32) {
        int s0 = vals[base + g];
        int s1 = vals[base + 16 + g];
        u16x8 v0 = *(const u16x8*)(tab + (size_t)s0 * D);
        u16x8 v1 = *(const u16x8*)(tab + (size_t)s1 * D);
#pragma unroll
        for (int j = 0; j < 8; ++j) acc[j] += bf2f(v0[j]) + bf2f(v1[j]);
    }
    for (; base + 16 <= end; base += 16) {
        int s0 = vals[base + g];
        u16x8 v0 = *(const u16x8*)(tab + (size_t)s0 * D);
#pragma unroll
        for (int j = 0; j < 8; ++j) acc[j] += bf2f(v0[j]);
    }
    int rem = end - base;
    if (g < rem) {
        int s0 = vals[base + g];
        u16x8 v0 = *(const u16x8*)(tab + (size_t)s0 * D);
#pragma unroll
        for (int j = 0; j < 8; ++j) acc[j] += bf2f(v0[j]);
    }
    // reduce across 16 groups (lane bits 2..5)
#pragma unroll
    for (int j = 0; j < 8; ++j) {
        acc[j] += __shfl_xor(acc[j], 4);
        acc[j] += __shfl_xor(acc[j], 8);
        acc[j] += __shfl_xor(acc[j], 16);
        acc[j] += __shfl_xor(acc[j], 32);
    }

    if (g == 0) {
        float inv = 1.0f / fmaxf((float)(end - beg), 1.0f);
        u16x8 mv;
#pragma unroll
        for (int j = 0; j < 8; ++j) mv[j] = f2bf(acc[j] * inv);
        *(u16x8*)(Am + (size_t)node * D + half * 32 + 8 * q) = mv;
    }
}

// ---------------------------------------------------------------------------
// gemm_h: dense MFMA over 16 nodes/block (4 waves x 16-col tiles).
// H = relu(Am@Wn + X@Ws + b) -> hh (bf16). A-frags read straight from
// global Am/Xh (sequential); B-frags from global bf16 W (L1-hot).
// Fragment conventions identical to the R11-verified kernel.
// ---------------------------------------------------------------------------
__global__ __launch_bounds__(256) void gemm_h(
    const unsigned short* __restrict__ Am,
    const unsigned short* __restrict__ Xh,
    const unsigned short* __restrict__ Whn,
    const unsigned short* __restrict__ Whs,
    const float* __restrict__ bias,
    unsigned short* __restrict__ hh, int nNodes) {
    int t = threadIdx.x;
    int w = t >> 6;        // wave = col tile 0..3
    int lane = t & 63;
    int c = lane & 15;     // A row within tile / B+C col
    int hi = lane >> 4;    // k-group / C row-group
    int nb = blockIdx.x * 16;
    int arow = min(nb + c, nNodes - 1);

    f32x4 acc;
    float bv = bias[w * 16 + c];
    acc[0] = bv; acc[1] = bv; acc[2] = bv; acc[3] = bv;
#pragma unroll
    for (int kh = 0; kh < 2; ++kh) {
        bf16x8 aA = *(const bf16x8*)(Am + (size_t)arow * D + kh * 32 + hi * 8);
        bf16x8 aX = *(const bf16x8*)(Xh + (size_t)arow * D + kh * 32 + hi * 8);
        bf16x8 bN, bS;
        int kb = kh * 32 + hi * 8;
#pragma unroll
        for (int j = 0; j < 8; ++j) {
            bN[j] = (short)Whn[(size_t)(kb + j) * D + w * 16 + c];
            bS[j] = (short)Whs[(size_t)(kb + j) * D + w * 16 + c];
        }
        acc = __builtin_amdgcn_mfma_f32_16x16x32_bf16(aA, bN, acc, 0, 0, 0);
        acc = __builtin_amdgcn_mfma_f32_16x16x32_bf16(aX, bS, acc, 0, 0, 0);
    }
    // C/D layout (verified): col = lane&15, row = (lane>>4)*4 + reg
#pragma unroll
    for (int r = 0; r < 4; ++r) {
        int node = nb + hi * 4 + r;
        if (node < nNodes)
            hh[(size_t)node * D + w * 16 + c] = f2bf(fmaxf(acc[r], 0.0f));
    }
}

// ---------------------------------------------------------------------------
// m_half: per node wave over outgoing edges; gather HALF-rows of hh,
// squared diffs vs in-register hn; tanh(mean) -> out[n][half].
// off[nNodes+node] indexes vals [E,2E) directly.
// ---------------------------------------------------------------------------
__global__ __launch_bounds__(256) void m_half(
    const unsigned short* __restrict__ hh,    // [N*D] bf16
    const int* __restrict__ off,              // [2N+1]
    const unsigned short* __restrict__ vals,  // [2E]
    float* __restrict__ out, int nNodes, int half) {
    int t = threadIdx.x;
    int li = t >> 6;
    int lane = t & 63;
    int g = lane >> 2;     // edge group 0..15
    int q = lane & 3;      // ushort8 chunk: half dims 8q..8q+7
    int node = blockIdx.x * 4 + li;
    if (node >= nNodes) return;

    const unsigned short* tab = hh + half * 32 + 8 * q;
    u16x8 hv = *(const u16x8*)(tab + (size_t)node * D);
    float hn[8];
#pragma unroll
    for (int j = 0; j < 8; ++j) hn[j] = bf2f(hv[j]);

    int beg = off[nNodes + node];
    int end = off[nNodes + node + 1];

    float acc[8];
#pragma unroll
    for (int j = 0; j < 8; ++j) acc[j] = 0.f;

    int base = beg;
    for (; base + 32 <= end; base += 32) {
        int t0 = vals[base + g];
        int t1 = vals[base + 16 + g];
        u16x8 u0 = *(const u16x8*)(tab + (size_t)t0 * D);
        u16x8 u1 = *(const u16x8*)(tab + (size_t)t1 * D);
#pragma unroll
        for (int j = 0; j < 8; ++j) {
            float d0 = hn[j] - bf2f(u0[j]);
            float d1 = hn[j] - bf2f(u1[j]);
            acc[j] += d0 * d0 + d1 * d1;
        }
    }
    for (; base + 16 <= end; base += 16) {
        int t0 = vals[base + g];
        u16x8 u0 = *(const u16x8*)(tab + (size_t)t0 * D);
#pragma unroll
        for (int j = 0; j < 8; ++j) {
            float d0 = hn[j] - bf2f(u0[j]);
            acc[j] += d0 * d0;
        }
    }
    int rem = end - base;
    if (g < rem) {
        int t0 = vals[base + g];
        u16x8 u0 = *(const u16x8*)(tab + (size_t)t0 * D);
#pragma unroll
        for (int j = 0; j < 8; ++j) {
            float d0 = hn[j] - bf2f(u0[j]);
            acc[j] += d0 * d0;
        }
    }
#pragma unroll
    for (int j = 0; j < 8; ++j) {
        acc[j] += __shfl_xor(acc[j], 4);
        acc[j] += __shfl_xor(acc[j], 8);
        acc[j] += __shfl_xor(acc[j], 16);
        acc[j] += __shfl_xor(acc[j], 32);
    }

    if (g == 0) {
        float inv = 1.0f / fmaxf((float)(end - beg), 1.0f);
        float* po = out + (size_t)node * D + half * 32 + 8 * q;
        float4 r0, r1;
        r0.x = tanhf(acc[0] * inv); r0.y = tanhf(acc[1] * inv);
        r0.z = tanhf(acc[2] * inv); r0.w = tanhf(acc[3] * inv);
        r1.x = tanhf(acc[4] * inv); r1.y = tanhf(acc[5] * inv);
        r1.z = tanhf(acc[6] * inv); r1.w = tanhf(acc[7] * inv);
        ((float4*)po)[0] = r0;
        ((float4*)po)[1] = r1;
    }
}

extern "C" void kernel_launch(void* const* d_in, const int* in_sizes, int n_in,
                              void* d_out, int out_size, void* d_ws, size_t ws_size,
                              hipStream_t stream) {
    const float* X  = (const float*)d_in[0];
    const int*   ei = (const int*)d_in[1];   // int32 (JAX canonicalized)
    const float* Wn = (const float*)d_in[2];
    const float* Ws = (const float*)d_in[3];
    const float* b  = (const float*)d_in[4];
    float* out = (float*)d_out;

    int nNodes = in_sizes[0] / D;
    int nEdges = in_sizes[1] / 2;
    const int* src = ei;
    const int* dst = ei + nEdges;

    int n2 = 2 * nNodes;                       // item key space
    int K = (n2 + STEP - 1) / STEP;            // 391 for N=50k
    int WGs = (nEdges + PART_CHUNK - 1) / PART_CHUNK;  // 391
    int nCnt = K * WGs;
    int nb = (nCnt + SCAN_ELEMS - 1) / SCAN_ELEMS;
    int totalItems = 2 * nEdges;

    // workspace (16B-aligned sections, 4B elems):
    // cnt[K*WGs] | scanned[K*WGs] | bsum[256] | off[2N+1] | part[2E u32]
    // | vals[2E u16] | Xh[N*D u16] | hh[N*D u16] | Am[N*D u16] | Whn | Whs
    size_t o = 0;
    auto align4 = [](size_t x) { return (x + 3) & ~(size_t)3; };
    int* cnt     = (int*)d_ws;                 o = align4((size_t)nCnt);
    int* scanned = (int*)d_ws + o;             o = align4(o + (size_t)nCnt);
    int* bsum    = (int*)d_ws + o;             o = align4(o + 256);
    int* off     = (int*)d_ws + o;             o = align4(o + (size_t)n2 + 1);
    unsigned int* part = (unsigned int*)((int*)d_ws + o);
    o = align4(o + 2 * (size_t)nEdges);
    unsigned short* vals = (unsigned short*)((int*)d_ws + o);
    o = align4(o + (size_t)nEdges);            // 2E u16 == E ints
    unsigned short* Xh = (unsigned short*)((int*)d_ws + o);
    o = align4(o + (size_t)nNodes * D / 2);    // N*D u16
    unsigned short* hh = (unsigned short*)((int*)d_ws + o);
    o = align4(o + (size_t)nNodes * D / 2);
    unsigned short* Am = (unsigned short*)((int*)d_ws + o);
    o = align4(o + (size_t)nNodes * D / 2);
    unsigned short* Whn = (unsigned short*)((int*)d_ws + o);
    o = align4(o + (size_t)(D * D) / 2);
    unsigned short* Whs = (unsigned short*)((int*)d_ws + o);

    int n8x = nNodes * D / 8;
    int n8w = D * D / 8;
    int cvtBlocks = (n8x + 2 * n8w + 255) / 256;
    to_bf16_all<<<cvtBlocks, 256, 0, stream>>>(X, Wn, Ws, Xh, Whn, Whs, n8x, n8w);

    part_hist<<<WGs, 256, 0, stream>>>(src, dst, cnt, nEdges, nNodes, K, WGs);
    scan_part<<<nb, 256, 0, stream>>>(cnt, bsum, nCnt);
    scan_tops<<<1, 256, 0, stream>>>(bsum, nb);
    scan_final<<<nb, 256, 0, stream>>>(cnt, bsum, scanned, nCnt);
    part_write<<<WGs, 256, 0, stream>>>(src, dst, scanned, part, nEdges, nNodes, K, WGs);
    csr_build<<<K, STEP, 0, stream>>>(part, scanned, vals, off, n2, K, WGs, totalItems);

    int gBlocks = (nNodes + 3) / 4;
    agg_mean_half<<<gBlocks, 256, 0, stream>>>(Xh, off, vals, Am, nNodes, 0);
    agg_mean_half<<<gBlocks, 256, 0, stream>>>(Xh, off, vals, Am, nNodes, 1);

    int hBlocks = (nNodes + 15) / 16;
    gemm_h<<<hBlocks, 256, 0, stream>>>(Am, Xh, Whn, Whs, b, hh, nNodes);

    m_half<<<gBlocks, 256, 0, stream>>>(hh, off, vals, out, nNodes, 0);
    m_half<<<gBlocks, 256, 0, stream>>>(hh, off, vals, out, nNodes, 1);
}

// Round 14
// 106.315 us; speedup vs baseline: 1.4719x; 1.4719x over previous
//
#include <hip/hip_runtime.h>
#include <math.h>

#define D 64
#define SCAN_ELEMS 1024    // elements per scan block (256 thr x 4)
#define STEP 256           // nodes per partition bucket (key space 2N)
#define SHIFT 8            // log2(STEP)
#define PART_CHUNK 2048    // edges per partition WG

// Node ids fit u16 (N=50000 < 65536). Partition items: (local_key<<16)|other.
// X, h, W staged bf16. GEMM on MFMA (R11-verified fragment conventions).
// R13 lesson: dim-half split doubles line-granular traffic (64B of a 128B
// line) — reverted. This round: 2 independent node streams per wave in
// m_gather (deeper MLP), to_bf16 merged into part_hist.

typedef __attribute__((ext_vector_type(8))) short bf16x8;
typedef __attribute__((ext_vector_type(8))) unsigned short u16x8;
typedef __attribute__((ext_vector_type(4))) float f32x4;

__device__ inline unsigned short f2bf(float f) {   // round-to-nearest-even
    unsigned u = __float_as_uint(f);
    return (unsigned short)((u + 0x7FFFu + ((u >> 16) & 1u)) >> 16);
}
__device__ inline float bf2f(unsigned short h) {
    return __uint_as_float(((unsigned)h) << 16);
}

// ---------------------------------------------------------------------------
// part_hist_cvt: blocks [0,WGs) do the per-WG bucket histogram; blocks
// [WGs, WGs+cvtBlocks) convert X/Wn/Ws -> bf16 (independent work, one launch).
// ---------------------------------------------------------------------------
__global__ __launch_bounds__(256) void part_hist_cvt(
    const int* __restrict__ src, const int* __restrict__ dst,
    int* __restrict__ cnt, int nE, int nN, int K, int WGs,
    const float* __restrict__ X, const float* __restrict__ Wn,
    const float* __restrict__ Ws, unsigned short* __restrict__ Xh,
    unsigned short* __restrict__ Whn, unsigned short* __restrict__ Whs,
    int n8x, int n8w) {
    __shared__ int lh[1024];
    int wg = blockIdx.x;
    if (wg >= WGs) {
        int i = (wg - WGs) * 256 + threadIdx.x;
        const float* in; unsigned short* outh; int idx;
        if (i < n8x) { in = X; outh = Xh; idx = i; }
        else if (i < n8x + n8w) { in = Wn; outh = Whn; idx = i - n8x; }
        else if (i < n8x + 2 * n8w) { in = Ws; outh = Whs; idx = i - n8x - n8w; }
        else return;
        const float4* p = (const float4*)in + (size_t)idx * 2;
        float4 a = p[0], b = p[1];
        union { unsigned short us[8]; uint4 v; } u;
        u.us[0] = f2bf(a.x); u.us[1] = f2bf(a.y); u.us[2] = f2bf(a.z); u.us[3] = f2bf(a.w);
        u.us[4] = f2bf(b.x); u.us[5] = f2bf(b.y); u.us[6] = f2bf(b.z); u.us[7] = f2bf(b.w);
        ((uint4*)outh)[idx] = u.v;
        return;
    }
    for (int i = threadIdx.x; i < K; i += 256) lh[i] = 0;
    __syncthreads();
    int base = wg * PART_CHUNK;
    int lim = min(base + PART_CHUNK, nE);
    for (int e = base + threadIdx.x; e < lim; e += 256) {
        int s = src[e], t = dst[e];
        atomicAdd(&lh[t >> SHIFT], 1);
        atomicAdd(&lh[(nN + s) >> SHIFT], 1);
    }
    __syncthreads();
    for (int b = threadIdx.x; b < K; b += 256) cnt[b * WGs + wg] = lh[b];
}

// ---------------------------------------------------------------------------
// scan pass 1: per-block sums
// ---------------------------------------------------------------------------
__global__ __launch_bounds__(256) void scan_part(
    const int* __restrict__ in, int* __restrict__ bsum, int n) {
    __shared__ int sdata[256];
    int b = blockIdx.x, t = threadIdx.x;
    int base = b * SCAN_ELEMS + t * 4;
    int s = 0;
#pragma unroll
    for (int k = 0; k < 4; ++k) { int i = base + k; if (i < n) s += in[i]; }
    sdata[t] = s;
    __syncthreads();
    for (int o = 128; o > 0; o >>= 1) {
        if (t < o) sdata[t] += sdata[t + o];
        __syncthreads();
    }
    if (t == 0) bsum[b] = sdata[0];
}

// ---------------------------------------------------------------------------
// scan pass 2: exclusive scan of block sums in place (nb <= 256)
// ---------------------------------------------------------------------------
__global__ __launch_bounds__(256) void scan_tops(int* __restrict__ bsum, int nb) {
    __shared__ int sd[256];
    int t = threadIdx.x;
    int v = (t < nb) ? bsum[t] : 0;
    sd[t] = v;
    __syncthreads();
    for (int o = 1; o < 256; o <<= 1) {
        int u = (t >= o) ? sd[t - o] : 0;
        __syncthreads();
        sd[t] += u;
        __syncthreads();
    }
    if (t < nb) bsum[t] = sd[t] - v;   // exclusive
}

// ---------------------------------------------------------------------------
// scan pass 3: per-chunk exclusive scan + block offset -> out
// ---------------------------------------------------------------------------
__global__ __launch_bounds__(256) void scan_final(
    const int* __restrict__ in, const int* __restrict__ bsum,
    int* __restrict__ out, int n) {
    __shared__ int sth[256];
    int b = blockIdx.x, t = threadIdx.x;
    int base = b * SCAN_ELEMS + t * 4;
    int v[4]; int s = 0;
#pragma unroll
    for (int k = 0; k < 4; ++k) { int i = base + k; v[k] = (i < n) ? in[i] : 0; s += v[k]; }
    sth[t] = s;
    __syncthreads();
    for (int o = 1; o < 256; o <<= 1) {
        int u = (t >= o) ? sth[t - o] : 0;
        __syncthreads();
        sth[t] += u;
        __syncthreads();
    }
    int run = sth[t] - s + bsum[b];
#pragma unroll
    for (int k = 0; k < 4; ++k) {
        int i = base + k;
        if (i < n) { out[i] = run; run += v[k]; }
    }
}

// ---------------------------------------------------------------------------
// part_write: each WG writes items into ITS OWN contiguous slice of each
// bucket region. Single owner + temporally compact -> writeback ~= payload.
// ---------------------------------------------------------------------------
__global__ __launch_bounds__(256) void part_write(
    const int* __restrict__ src, const int* __restrict__ dst,
    const int* __restrict__ scanned, unsigned int* __restrict__ part,
    int nE, int nN, int K, int WGs) {
    __shared__ int cur[1024];
    int wg = blockIdx.x;
    for (int b = threadIdx.x; b < K; b += 256) cur[b] = scanned[b * WGs + wg];
    __syncthreads();
    int base = wg * PART_CHUNK;
    int lim = min(base + PART_CHUNK, nE);
    for (int e = base + threadIdx.x; e < lim; e += 256) {
        int s = src[e], t = dst[e];
        int k1 = t;
        int p1 = atomicAdd(&cur[k1 >> SHIFT], 1);
        part[p1] = ((unsigned)(k1 & (STEP - 1)) << 16) | (unsigned)s;
        int k2 = nN + s;
        int p2 = atomicAdd(&cur[k2 >> SHIFT], 1);
        part[p2] = ((unsigned)(k2 & (STEP - 1)) << 16) | (unsigned)t;
    }
}

// ---------------------------------------------------------------------------
// csr_build: one WG per bucket. LDS degree count + prefix -> off[] exact,
// then scatter u16 vals into the WG-private region.
// ---------------------------------------------------------------------------
__global__ __launch_bounds__(256) void csr_build(
    const unsigned int* __restrict__ part, const int* __restrict__ scanned,
    unsigned short* __restrict__ vals, int* __restrict__ off,
    int n2, int K, int WGs, int totalItems) {
    __shared__ int deg[STEP];
    __shared__ int pfx[STEP];
    int b = blockIdx.x, t = threadIdx.x;
    int base = scanned[b * WGs];
    int endi = (b + 1 < K) ? scanned[(b + 1) * WGs] : totalItems;

    deg[t] = 0;
    __syncthreads();
    for (int i = base + t; i < endi; i += 256)
        atomicAdd(&deg[part[i] >> 16], 1);
    __syncthreads();

    pfx[t] = deg[t];
    __syncthreads();
    for (int o = 1; o < STEP; o <<= 1) {
        int u = (t >= o) ? pfx[t - o] : 0;
        __syncthreads();
        pfx[t] += u;
        __syncthreads();
    }
    int ex = pfx[t] - deg[t];
    int g = b * STEP + t;
    if (g < n2) off[g] = base + ex;
    if (b == K - 1 && t == 0) off[n2] = totalItems;
    deg[t] = ex;           // reuse as bucket-local cursor
    __syncthreads();

    for (int i = base + t; i < endi; i += 256) {
        unsigned u = part[i];
        int l = (int)(u >> 16);
        int p = atomicAdd(&deg[l], 1);
        vals[base + p] = (unsigned short)(u & 0xffffu);
    }
}

// ---------------------------------------------------------------------------
// Kernel A (unchanged from R12): 512 thr = 8 node-waves. Gather 8 groups x
// 8 lanes ushort8; butterfly-reduce; bf16 LDS stage (4608B); waves 0-3
// compute H = relu(Aagg@Wn + Ax@Ws + b) via mfma_f32_16x16x32_bf16.
// ---------------------------------------------------------------------------
#define ANODES 8
#define ROWB 144   // row stride in bytes: 72 u16 (64 data + 8 pad)
__global__ __launch_bounds__(512) void agg_gemm(
    const unsigned short* __restrict__ Xh,    // [N*D] bf16
    const int* __restrict__ off,              // [2N+1]
    const unsigned short* __restrict__ vals,  // [2E]
    const unsigned short* __restrict__ Whn,   // [64*64] bf16
    const unsigned short* __restrict__ Whs,   // [64*64] bf16
    const float* __restrict__ bias,
    unsigned short* __restrict__ hh, int nNodes) {
    __shared__ __align__(16) unsigned short rows[2][16][72];

    int t = threadIdx.x;
    if (t < 288) {
        int b = t / 144, r = t - b * 144;
        *(unsigned long long*)((char*)&rows[b][8][0] + r * 8) = 0ULL;
    }

    int li = t >> 6;       // wave id = local node 0..7
    int lane = t & 63;
    int g = lane >> 3;     // edge group 0..7
    int q = lane & 7;      // ushort8 chunk: dims 8q..8q+7
    int bb = blockIdx.x * ANODES;
    int node = bb + li;

    float acc[8];
#pragma unroll
    for (int j = 0; j < 8; ++j) acc[j] = 0.f;

    int beg = 0, end = 0;
    if (node < nNodes) { beg = off[node]; end = off[node + 1]; }

    int base = beg;
    for (; base + 16 <= end; base += 16) {
        int s0 = vals[base + g];
        int s1 = vals[base + 8 + g];
        u16x8 v0 = ((const u16x8*)(Xh + (size_t)s0 * D))[q];
        u16x8 v1 = ((const u16x8*)(Xh + (size_t)s1 * D))[q];
#pragma unroll
        for (int j = 0; j < 8; ++j) acc[j] += bf2f(v0[j]) + bf2f(v1[j]);
    }
    for (; base + 8 <= end; base += 8) {
        int s0 = vals[base + g];
        u16x8 v0 = ((const u16x8*)(Xh + (size_t)s0 * D))[q];
#pragma unroll
        for (int j = 0; j < 8; ++j) acc[j] += bf2f(v0[j]);
    }
    int rem = end - base;
    if (g < rem) {
        int s0 = vals[base + g];
        u16x8 v0 = ((const u16x8*)(Xh + (size_t)s0 * D))[q];
#pragma unroll
        for (int j = 0; j < 8; ++j) acc[j] += bf2f(v0[j]);
    }
#pragma unroll
    for (int j = 0; j < 8; ++j) {
        acc[j] += __shfl_xor(acc[j], 8);
        acc[j] += __shfl_xor(acc[j], 16);
        acc[j] += __shfl_xor(acc[j], 32);
    }

    if (node < nNodes && g == 0) {
        float inv = 1.0f / fmaxf((float)(end - beg), 1.0f);
        u16x8 mv;
#pragma unroll
        for (int j = 0; j < 8; ++j) mv[j] = f2bf(acc[j] * inv);
        *(u16x8*)((char*)&rows[0][li][0] + q * 16) = mv;
        u16x8 xv = ((const u16x8*)(Xh + (size_t)node * D))[q];
        *(u16x8*)((char*)&rows[1][li][0] + q * 16) = xv;
    }
    __syncthreads();

    if (li >= 4) return;
    int c = lane & 15;     // A row index / B+C col index
    int hi = lane >> 4;    // k-group / C row-group
    f32x4 accm;
    float bv = bias[li * 16 + c];
    accm[0] = bv; accm[1] = bv; accm[2] = bv; accm[3] = bv;
#pragma unroll
    for (int kh = 0; kh < 2; ++kh) {
        bf16x8 aA = *(const bf16x8*)((const char*)&rows[0][0][0] + c * ROWB + kh * 64 + hi * 16);
        bf16x8 aX = *(const bf16x8*)((const char*)&rows[1][0][0] + c * ROWB + kh * 64 + hi * 16);
        bf16x8 bN, bS;
        int kb = kh * 32 + hi * 8;
#pragma unroll
        for (int j = 0; j < 8; ++j) {
            bN[j] = (short)Whn[(size_t)(kb + j) * D + li * 16 + c];
            bS[j] = (short)Whs[(size_t)(kb + j) * D + li * 16 + c];
        }
        accm = __builtin_amdgcn_mfma_f32_16x16x32_bf16(aA, bN, accm, 0, 0, 0);
        accm = __builtin_amdgcn_mfma_f32_16x16x32_bf16(aX, bS, accm, 0, 0, 0);
    }
    // C/D layout (m89-verified): col = lane&15, row = (lane>>4)*4 + reg
#pragma unroll
    for (int r = 0; r < 4; ++r) {
        int row = hi * 4 + r;
        if (row < 8) {
            int n2a = bb + row;
            if (n2a < nNodes)
                hh[(size_t)n2a * D + li * 16 + c] = f2bf(fmaxf(accm[r], 0.0f));
        }
    }
}

// ---------------------------------------------------------------------------
// Kernel B: TWO independent node streams per wave (lane halves), 4 groups x
// 8 lanes per node, unroll 4 -> 4KB in flight/wave (2x R12) + 2 dependency
// chains. 8 nodes/block. Squared diffs vs in-register hn; tanh(mean) -> out.
// off[nNodes+node] indexes vals [E,2E) directly.
// ---------------------------------------------------------------------------
__global__ __launch_bounds__(256) void m_gather(
    const unsigned short* __restrict__ hh,    // [N*D] bf16
    const int* __restrict__ off,              // [2N+1], src section at [N..2N]
    const unsigned short* __restrict__ vals,  // [2E]
    float* __restrict__ out, int nNodes) {
    int t = threadIdx.x;
    int w = t >> 6;          // wave 0..3
    int lane = t & 63;
    int half = lane >> 5;    // node stream within wave
    int gg = (lane >> 3) & 3;  // group within node 0..3
    int q = lane & 7;        // ushort8 chunk: dims 8q..8q+7
    int node = blockIdx.x * 8 + w * 2 + half;
    bool valid = node < nNodes;

    u16x8 hv = {};
    int beg = 0, end = 0;
    if (valid) {
        hv = ((const u16x8*)(hh + (size_t)node * D))[q];
        beg = off[nNodes + node];
        end = off[nNodes + node + 1];
    }
    float hn[8];
#pragma unroll
    for (int j = 0; j < 8; ++j) hn[j] = bf2f(hv[j]);

    float acc[8];
#pragma unroll
    for (int j = 0; j < 8; ++j) acc[j] = 0.f;

    int base = beg;
    for (; base + 16 <= end; base += 16) {
        int t0 = vals[base + gg];
        int t1 = vals[base + 4 + gg];
        int t2 = vals[base + 8 + gg];
        int t3 = vals[base + 12 + gg];
        u16x8 u0 = ((const u16x8*)(hh + (size_t)t0 * D))[q];
        u16x8 u1 = ((const u16x8*)(hh + (size_t)t1 * D))[q];
        u16x8 u2 = ((const u16x8*)(hh + (size_t)t2 * D))[q];
        u16x8 u3 = ((const u16x8*)(hh + (size_t)t3 * D))[q];
#pragma unroll
        for (int j = 0; j < 8; ++j) {
            float d0 = hn[j] - bf2f(u0[j]);
            float d1 = hn[j] - bf2f(u1[j]);
            float d2 = hn[j] - bf2f(u2[j]);
            float d3 = hn[j] - bf2f(u3[j]);
            acc[j] += d0 * d0 + d1 * d1 + d2 * d2 + d3 * d3;
        }
    }
    for (; base + 4 <= end; base += 4) {
        int t0 = vals[base + gg];
        u16x8 u0 = ((const u16x8*)(hh + (size_t)t0 * D))[q];
#pragma unroll
        for (int j = 0; j < 8; ++j) {
            float d0 = hn[j] - bf2f(u0[j]);
            acc[j] += d0 * d0;
        }
    }
    int rem = end - base;
    if (gg < rem) {
        int t0 = vals[base + gg];
        u16x8 u0 = ((const u16x8*)(hh + (size_t)t0 * D))[q];
#pragma unroll
        for (int j = 0; j < 8; ++j) {
            float d0 = hn[j] - bf2f(u0[j]);
            acc[j] += d0 * d0;
        }
    }
    // reduce across the 4 groups of this node stream (lane bits 3,4 only —
    // xor 8/16 stays within each 32-lane half, so streams never mix)
#pragma unroll
    for (int j = 0; j < 8; ++j) {
        acc[j] += __shfl_xor(acc[j], 8);
        acc[j] += __shfl_xor(acc[j], 16);
    }

    if (valid && gg == 0) {
        float inv = 1.0f / fmaxf((float)(end - beg), 1.0f);
        float4 r0, r1;
        r0.x = tanhf(acc[0] * inv); r0.y = tanhf(acc[1] * inv);
        r0.z = tanhf(acc[2] * inv); r0.w = tanhf(acc[3] * inv);
        r1.x = tanhf(acc[4] * inv); r1.y = tanhf(acc[5] * inv);
        r1.z = tanhf(acc[6] * inv); r1.w = tanhf(acc[7] * inv);
        ((float4*)(out + (size_t)node * D))[q * 2] = r0;
        ((float4*)(out + (size_t)node * D))[q * 2 + 1] = r1;
    }
}

extern "C" void kernel_launch(void* const* d_in, const int* in_sizes, int n_in,
                              void* d_out, int out_size, void* d_ws, size_t ws_size,
                              hipStream_t stream) {
    const float* X  = (const float*)d_in[0];
    const int*   ei = (const int*)d_in[1];   // int32 (JAX canonicalized)
    const float* Wn = (const float*)d_in[2];
    const float* Ws = (const float*)d_in[3];
    const float* b  = (const float*)d_in[4];
    float* out = (float*)d_out;

    int nNodes = in_sizes[0] / D;
    int nEdges = in_sizes[1] / 2;
    const int* src = ei;
    const int* dst = ei + nEdges;

    int n2 = 2 * nNodes;                       // item key space
    int K = (n2 + STEP - 1) / STEP;            // 391 for N=50k
    int WGs = (nEdges + PART_CHUNK - 1) / PART_CHUNK;  // 391
    int nCnt = K * WGs;
    int nb = (nCnt + SCAN_ELEMS - 1) / SCAN_ELEMS;
    int totalItems = 2 * nEdges;

    // workspace (16B-aligned sections, 4B elems):
    // cnt[K*WGs] | scanned[K*WGs] | bsum[256] | off[2N+1] | part[2E u32]
    // | vals[2E u16] | Xh[N*D u16] | hh[N*D u16] | Whn[4096 u16] | Whs[...]
    size_t o = 0;
    auto align4 = [](size_t x) { return (x + 3) & ~(size_t)3; };
    int* cnt     = (int*)d_ws;                 o = align4((size_t)nCnt);
    int* scanned = (int*)d_ws + o;             o = align4(o + (size_t)nCnt);
    int* bsum    = (int*)d_ws + o;             o = align4(o + 256);
    int* off     = (int*)d_ws + o;             o = align4(o + (size_t)n2 + 1);
    unsigned int* part = (unsigned int*)((int*)d_ws + o);
    o = align4(o + 2 * (size_t)nEdges);
    unsigned short* vals = (unsigned short*)((int*)d_ws + o);
    o = align4(o + (size_t)nEdges);            // 2E u16 == E ints
    unsigned short* Xh = (unsigned short*)((int*)d_ws + o);
    o = align4(o + (size_t)nNodes * D / 2);    // N*D u16
    unsigned short* hh = (unsigned short*)((int*)d_ws + o);
    o = align4(o + (size_t)nNodes * D / 2);
    unsigned short* Whn = (unsigned short*)((int*)d_ws + o);
    o = align4(o + (size_t)(D * D) / 2);
    unsigned short* Whs = (unsigned short*)((int*)d_ws + o);

    int n8x = nNodes * D / 8;
    int n8w = D * D / 8;
    int cvtBlocks = (n8x + 2 * n8w + 255) / 256;

    part_hist_cvt<<<WGs + cvtBlocks, 256, 0, stream>>>(
        src, dst, cnt, nEdges, nNodes, K, WGs,
        X, Wn, Ws, Xh, Whn, Whs, n8x, n8w);
    scan_part<<<nb, 256, 0, stream>>>(cnt, bsum, nCnt);
    scan_tops<<<1, 256, 0, stream>>>(bsum, nb);
    scan_final<<<nb, 256, 0, stream>>>(cnt, bsum, scanned, nCnt);
    part_write<<<WGs, 256, 0, stream>>>(src, dst, scanned, part, nEdges, nNodes, K, WGs);
    csr_build<<<K, STEP, 0, stream>>>(part, scanned, vals, off, n2, K, WGs, totalItems);

    int aBlocks = (nNodes + ANODES - 1) / ANODES;
    agg_gemm<<<aBlocks, 512, 0, stream>>>(Xh, off, vals, Whn, Whs, b, hh, nNodes);
    int mBlocks = (nNodes + 7) / 8;
    m_gather<<<mBlocks, 256, 0, stream>>>(hh, off, vals, out, nNodes);
}

// Round 15
// 101.097 us; speedup vs baseline: 1.5479x; 1.0516x over previous
//
#include <hip/hip_runtime.h>
#include <math.h>

#define D 64
#define SCAN_ELEMS 1024    // elements per scan block (256 thr x 4)
#define STEP 256           // nodes per partition bucket (key space 2N)
#define SHIFT 8            // log2(STEP)
#define PART_CHUNK 2048    // edges per partition WG

// Node ids fit u16 (N=50000 < 65536). Partition items: (local_key<<16)|other.
// X, h, W staged bf16. GEMM on MFMA (verified fragment conventions).
// R14 lesson: gathers are latency/MLP-bound — 2 independent node streams
// per wave (4KB in flight) is the fix. Applied to BOTH gather kernels now;
// agg_gemm block covers 16 nodes -> MFMA M-dim fully used (no pad rows).

typedef __attribute__((ext_vector_type(8))) short bf16x8;
typedef __attribute__((ext_vector_type(8))) unsigned short u16x8;
typedef __attribute__((ext_vector_type(4))) float f32x4;

__device__ inline unsigned short f2bf(float f) {   // round-to-nearest-even
    unsigned u = __float_as_uint(f);
    return (unsigned short)((u + 0x7FFFu + ((u >> 16) & 1u)) >> 16);
}
__device__ inline float bf2f(unsigned short h) {
    return __uint_as_float(((unsigned)h) << 16);
}

// ---------------------------------------------------------------------------
// part_hist_cvt: blocks [0,WGs) do the per-WG bucket histogram; blocks
// [WGs, WGs+cvtBlocks) convert X/Wn/Ws -> bf16 (independent work, one launch).
// ---------------------------------------------------------------------------
__global__ __launch_bounds__(256) void part_hist_cvt(
    const int* __restrict__ src, const int* __restrict__ dst,
    int* __restrict__ cnt, int nE, int nN, int K, int WGs,
    const float* __restrict__ X, const float* __restrict__ Wn,
    const float* __restrict__ Ws, unsigned short* __restrict__ Xh,
    unsigned short* __restrict__ Whn, unsigned short* __restrict__ Whs,
    int n8x, int n8w) {
    __shared__ int lh[1024];
    int wg = blockIdx.x;
    if (wg >= WGs) {
        int i = (wg - WGs) * 256 + threadIdx.x;
        const float* in; unsigned short* outh; int idx;
        if (i < n8x) { in = X; outh = Xh; idx = i; }
        else if (i < n8x + n8w) { in = Wn; outh = Whn; idx = i - n8x; }
        else if (i < n8x + 2 * n8w) { in = Ws; outh = Whs; idx = i - n8x - n8w; }
        else return;
        const float4* p = (const float4*)in + (size_t)idx * 2;
        float4 a = p[0], b = p[1];
        union { unsigned short us[8]; uint4 v; } u;
        u.us[0] = f2bf(a.x); u.us[1] = f2bf(a.y); u.us[2] = f2bf(a.z); u.us[3] = f2bf(a.w);
        u.us[4] = f2bf(b.x); u.us[5] = f2bf(b.y); u.us[6] = f2bf(b.z); u.us[7] = f2bf(b.w);
        ((uint4*)outh)[idx] = u.v;
        return;
    }
    for (int i = threadIdx.x; i < K; i += 256) lh[i] = 0;
    __syncthreads();
    int base = wg * PART_CHUNK;
    int lim = min(base + PART_CHUNK, nE);
    for (int e = base + threadIdx.x; e < lim; e += 256) {
        int s = src[e], t = dst[e];
        atomicAdd(&lh[t >> SHIFT], 1);
        atomicAdd(&lh[(nN + s) >> SHIFT], 1);
    }
    __syncthreads();
    for (int b = threadIdx.x; b < K; b += 256) cnt[b * WGs + wg] = lh[b];
}

// ---------------------------------------------------------------------------
// scan pass 1: per-block sums
// ---------------------------------------------------------------------------
__global__ __launch_bounds__(256) void scan_part(
    const int* __restrict__ in, int* __restrict__ bsum, int n) {
    __shared__ int sdata[256];
    int b = blockIdx.x, t = threadIdx.x;
    int base = b * SCAN_ELEMS + t * 4;
    int s = 0;
#pragma unroll
    for (int k = 0; k < 4; ++k) { int i = base + k; if (i < n) s += in[i]; }
    sdata[t] = s;
    __syncthreads();
    for (int o = 128; o > 0; o >>= 1) {
        if (t < o) sdata[t] += sdata[t + o];
        __syncthreads();
    }
    if (t == 0) bsum[b] = sdata[0];
}

// ---------------------------------------------------------------------------
// scan pass 2: exclusive scan of block sums in place (nb <= 256)
// ---------------------------------------------------------------------------
__global__ __launch_bounds__(256) void scan_tops(int* __restrict__ bsum, int nb) {
    __shared__ int sd[256];
    int t = threadIdx.x;
    int v = (t < nb) ? bsum[t] : 0;
    sd[t] = v;
    __syncthreads();
    for (int o = 1; o < 256; o <<= 1) {
        int u = (t >= o) ? sd[t - o] : 0;
        __syncthreads();
        sd[t] += u;
        __syncthreads();
    }
    if (t < nb) bsum[t] = sd[t] - v;   // exclusive
}

// ---------------------------------------------------------------------------
// scan pass 3: per-chunk exclusive scan + block offset -> out
// ---------------------------------------------------------------------------
__global__ __launch_bounds__(256) void scan_final(
    const int* __restrict__ in, const int* __restrict__ bsum,
    int* __restrict__ out, int n) {
    __shared__ int sth[256];
    int b = blockIdx.x, t = threadIdx.x;
    int base = b * SCAN_ELEMS + t * 4;
    int v[4]; int s = 0;
#pragma unroll
    for (int k = 0; k < 4; ++k) { int i = base + k; v[k] = (i < n) ? in[i] : 0; s += v[k]; }
    sth[t] = s;
    __syncthreads();
    for (int o = 1; o < 256; o <<= 1) {
        int u = (t >= o) ? sth[t - o] : 0;
        __syncthreads();
        sth[t] += u;
        __syncthreads();
    }
    int run = sth[t] - s + bsum[b];
#pragma unroll
    for (int k = 0; k < 4; ++k) {
        int i = base + k;
        if (i < n) { out[i] = run; run += v[k]; }
    }
}

// ---------------------------------------------------------------------------
// part_write: each WG writes items into ITS OWN contiguous slice of each
// bucket region. Single owner + temporally compact -> writeback ~= payload.
// ---------------------------------------------------------------------------
__global__ __launch_bounds__(256) void part_write(
    const int* __restrict__ src, const int* __restrict__ dst,
    const int* __restrict__ scanned, unsigned int* __restrict__ part,
    int nE, int nN, int K, int WGs) {
    __shared__ int cur[1024];
    int wg = blockIdx.x;
    for (int b = threadIdx.x; b < K; b += 256) cur[b] = scanned[b * WGs + wg];
    __syncthreads();
    int base = wg * PART_CHUNK;
    int lim = min(base + PART_CHUNK, nE);
    for (int e = base + threadIdx.x; e < lim; e += 256) {
        int s = src[e], t = dst[e];
        int k1 = t;
        int p1 = atomicAdd(&cur[k1 >> SHIFT], 1);
        part[p1] = ((unsigned)(k1 & (STEP - 1)) << 16) | (unsigned)s;
        int k2 = nN + s;
        int p2 = atomicAdd(&cur[k2 >> SHIFT], 1);
        part[p2] = ((unsigned)(k2 & (STEP - 1)) << 16) | (unsigned)t;
    }
}

// ---------------------------------------------------------------------------
// csr_build: one WG per bucket. LDS degree count + prefix -> off[] exact,
// then scatter u16 vals into the WG-private region.
// ---------------------------------------------------------------------------
__global__ __launch_bounds__(256) void csr_build(
    const unsigned int* __restrict__ part, const int* __restrict__ scanned,
    unsigned short* __restrict__ vals, int* __restrict__ off,
    int n2, int K, int WGs, int totalItems) {
    __shared__ int deg[STEP];
    __shared__ int pfx[STEP];
    int b = blockIdx.x, t = threadIdx.x;
    int base = scanned[b * WGs];
    int endi = (b + 1 < K) ? scanned[(b + 1) * WGs] : totalItems;

    deg[t] = 0;
    __syncthreads();
    for (int i = base + t; i < endi; i += 256)
        atomicAdd(&deg[part[i] >> 16], 1);
    __syncthreads();

    pfx[t] = deg[t];
    __syncthreads();
    for (int o = 1; o < STEP; o <<= 1) {
        int u = (t >= o) ? pfx[t - o] : 0;
        __syncthreads();
        pfx[t] += u;
        __syncthreads();
    }
    int ex = pfx[t] - deg[t];
    int g = b * STEP + t;
    if (g < n2) off[g] = base + ex;
    if (b == K - 1 && t == 0) off[n2] = totalItems;
    deg[t] = ex;           // reuse as bucket-local cursor
    __syncthreads();

    for (int i = base + t; i < endi; i += 256) {
        unsigned u = part[i];
        int l = (int)(u >> 16);
        int p = atomicAdd(&deg[l], 1);
        vals[base + p] = (unsigned short)(u & 0xffffu);
    }
}

// ---------------------------------------------------------------------------
// Kernel A: 512 thr = 8 waves x 2 node streams = 16 nodes/block. Gather:
// per stream 4 groups x 8 lanes, ushort8, unroll 4 -> 4KB in flight/wave.
// Reduce xor(8,16) within each 32-lane half. Stage 16 bf16 rows (means) +
// 16 X rows into 4608B LDS; waves 0-3 compute the full 16-row
// H = relu(Aagg@Wn + Ax@Ws + b) via mfma_f32_16x16x32_bf16 (M fully used).
// ---------------------------------------------------------------------------
#define ANODES 16
#define ROWB 144   // row stride in bytes: 72 u16 (64 data + 8 pad)
__global__ __launch_bounds__(512) void agg_gemm(
    const unsigned short* __restrict__ Xh,    // [N*D] bf16
    const int* __restrict__ off,              // [2N+1]
    const unsigned short* __restrict__ vals,  // [2E]
    const unsigned short* __restrict__ Whn,   // [64*64] bf16
    const unsigned short* __restrict__ Whs,   // [64*64] bf16
    const float* __restrict__ bias,
    unsigned short* __restrict__ hh, int nNodes) {
    __shared__ __align__(16) unsigned short rows[2][16][72];

    int t = threadIdx.x;
    int w = t >> 6;          // wave 0..7
    int lane = t & 63;
    int half = lane >> 5;    // node stream within wave
    int gg = (lane >> 3) & 3;  // group within node 0..3
    int q = lane & 7;        // ushort8 chunk: dims 8q..8q+7
    int bb = blockIdx.x * ANODES;
    int node = bb + w * 2 + half;
    bool valid = node < nNodes;

    float acc[8];
#pragma unroll
    for (int j = 0; j < 8; ++j) acc[j] = 0.f;

    int beg = 0, end = 0;
    if (valid) { beg = off[node]; end = off[node + 1]; }

    int base = beg;
    for (; base + 16 <= end; base += 16) {
        int s0 = vals[base + gg];
        int s1 = vals[base + 4 + gg];
        int s2 = vals[base + 8 + gg];
        int s3 = vals[base + 12 + gg];
        u16x8 v0 = ((const u16x8*)(Xh + (size_t)s0 * D))[q];
        u16x8 v1 = ((const u16x8*)(Xh + (size_t)s1 * D))[q];
        u16x8 v2 = ((const u16x8*)(Xh + (size_t)s2 * D))[q];
        u16x8 v3 = ((const u16x8*)(Xh + (size_t)s3 * D))[q];
#pragma unroll
        for (int j = 0; j < 8; ++j)
            acc[j] += (bf2f(v0[j]) + bf2f(v1[j])) + (bf2f(v2[j]) + bf2f(v3[j]));
    }
    for (; base + 4 <= end; base += 4) {
        int s0 = vals[base + gg];
        u16x8 v0 = ((const u16x8*)(Xh + (size_t)s0 * D))[q];
#pragma unroll
        for (int j = 0; j < 8; ++j) acc[j] += bf2f(v0[j]);
    }
    int rem = end - base;
    if (gg < rem) {
        int s0 = vals[base + gg];
        u16x8 v0 = ((const u16x8*)(Xh + (size_t)s0 * D))[q];
#pragma unroll
        for (int j = 0; j < 8; ++j) acc[j] += bf2f(v0[j]);
    }
    // reduce across the 4 groups of this stream (lane bits 3,4 only)
#pragma unroll
    for (int j = 0; j < 8; ++j) {
        acc[j] += __shfl_xor(acc[j], 8);
        acc[j] += __shfl_xor(acc[j], 16);
    }

    if (gg == 0) {
        float inv = 1.0f / fmaxf((float)(end - beg), 1.0f);
        u16x8 mv, xv;
        if (valid) {
#pragma unroll
            for (int j = 0; j < 8; ++j) mv[j] = f2bf(acc[j] * inv);
            xv = ((const u16x8*)(Xh + (size_t)node * D))[q];
        } else {
#pragma unroll
            for (int j = 0; j < 8; ++j) { mv[j] = 0; xv[j] = 0; }
        }
        int r = w * 2 + half;
        *(u16x8*)((char*)&rows[0][r][0] + q * 16) = mv;
        *(u16x8*)((char*)&rows[1][r][0] + q * 16) = xv;
    }
    __syncthreads();

    // ---- MFMA: waves 0..3, wave w owns col tile w (cols w*16..+15) -------
    if (w >= 4) return;
    int c = lane & 15;     // A row index / B+C col index
    int hi = lane >> 4;    // k-group / C row-group
    f32x4 accm;
    float bv = bias[w * 16 + c];
    accm[0] = bv; accm[1] = bv; accm[2] = bv; accm[3] = bv;
#pragma unroll
    for (int kh = 0; kh < 2; ++kh) {
        bf16x8 aA = *(const bf16x8*)((const char*)&rows[0][0][0] + c * ROWB + kh * 64 + hi * 16);
        bf16x8 aX = *(const bf16x8*)((const char*)&rows[1][0][0] + c * ROWB + kh * 64 + hi * 16);
        bf16x8 bN, bS;
        int kb = kh * 32 + hi * 8;
#pragma unroll
        for (int j = 0; j < 8; ++j) {
            bN[j] = (short)Whn[(size_t)(kb + j) * D + w * 16 + c];
            bS[j] = (short)Whs[(size_t)(kb + j) * D + w * 16 + c];
        }
        accm = __builtin_amdgcn_mfma_f32_16x16x32_bf16(aA, bN, accm, 0, 0, 0);
        accm = __builtin_amdgcn_mfma_f32_16x16x32_bf16(aX, bS, accm, 0, 0, 0);
    }
    // C/D layout (verified): col = lane&15, row = (lane>>4)*4 + reg
#pragma unroll
    for (int r = 0; r < 4; ++r) {
        int row = hi * 4 + r;
        int n2a = bb + row;
        if (n2a < nNodes)
            hh[(size_t)n2a * D + w * 16 + c] = f2bf(fmaxf(accm[r], 0.0f));
    }
}

// ---------------------------------------------------------------------------
// Kernel B (R14-proven): TWO independent node streams per wave, 4 groups x
// 8 lanes per node, unroll 4 -> 4KB in flight/wave. 8 nodes/block.
// Squared diffs vs in-register hn; tanh(mean) -> out.
// ---------------------------------------------------------------------------
__global__ __launch_bounds__(256) void m_gather(
    const unsigned short* __restrict__ hh,    // [N*D] bf16
    const int* __restrict__ off,              // [2N+1], src section at [N..2N]
    const unsigned short* __restrict__ vals,  // [2E]
    float* __restrict__ out, int nNodes) {
    int t = threadIdx.x;
    int w = t >> 6;          // wave 0..3
    int lane = t & 63;
    int half = lane >> 5;    // node stream within wave
    int gg = (lane >> 3) & 3;  // group within node 0..3
    int q = lane & 7;        // ushort8 chunk: dims 8q..8q+7
    int node = blockIdx.x * 8 + w * 2 + half;
    bool valid = node < nNodes;

    u16x8 hv = {};
    int beg = 0, end = 0;
    if (valid) {
        hv = ((const u16x8*)(hh + (size_t)node * D))[q];
        beg = off[nNodes + node];
        end = off[nNodes + node + 1];
    }
    float hn[8];
#pragma unroll
    for (int j = 0; j < 8; ++j) hn[j] = bf2f(hv[j]);

    float acc[8];
#pragma unroll
    for (int j = 0; j < 8; ++j) acc[j] = 0.f;

    int base = beg;
    for (; base + 16 <= end; base += 16) {
        int t0 = vals[base + gg];
        int t1 = vals[base + 4 + gg];
        int t2 = vals[base + 8 + gg];
        int t3 = vals[base + 12 + gg];
        u16x8 u0 = ((const u16x8*)(hh + (size_t)t0 * D))[q];
        u16x8 u1 = ((const u16x8*)(hh + (size_t)t1 * D))[q];
        u16x8 u2 = ((const u16x8*)(hh + (size_t)t2 * D))[q];
        u16x8 u3 = ((const u16x8*)(hh + (size_t)t3 * D))[q];
#pragma unroll
        for (int j = 0; j < 8; ++j) {
            float d0 = hn[j] - bf2f(u0[j]);
            float d1 = hn[j] - bf2f(u1[j]);
            float d2 = hn[j] - bf2f(u2[j]);
            float d3 = hn[j] - bf2f(u3[j]);
            acc[j] += d0 * d0 + d1 * d1 + d2 * d2 + d3 * d3;
        }
    }
    for (; base + 4 <= end; base += 4) {
        int t0 = vals[base + gg];
        u16x8 u0 = ((const u16x8*)(hh + (size_t)t0 * D))[q];
#pragma unroll
        for (int j = 0; j < 8; ++j) {
            float d0 = hn[j] - bf2f(u0[j]);
            acc[j] += d0 * d0;
        }
    }
    int rem = end - base;
    if (gg < rem) {
        int t0 = vals[base + gg];
        u16x8 u0 = ((const u16x8*)(hh + (size_t)t0 * D))[q];
#pragma unroll
        for (int j = 0; j < 8; ++j) {
            float d0 = hn[j] - bf2f(u0[j]);
            acc[j] += d0 * d0;
        }
    }
#pragma unroll
    for (int j = 0; j < 8; ++j) {
        acc[j] += __shfl_xor(acc[j], 8);
        acc[j] += __shfl_xor(acc[j], 16);
    }

    if (valid && gg == 0) {
        float inv = 1.0f / fmaxf((float)(end - beg), 1.0f);
        float4 r0, r1;
        r0.x = tanhf(acc[0] * inv); r0.y = tanhf(acc[1] * inv);
        r0.z = tanhf(acc[2] * inv); r0.w = tanhf(acc[3] * inv);
        r1.x = tanhf(acc[4] * inv); r1.y = tanhf(acc[5] * inv);
        r1.z = tanhf(acc[6] * inv); r1.w = tanhf(acc[7] * inv);
        ((float4*)(out + (size_t)node * D))[q * 2] = r0;
        ((float4*)(out + (size_t)node * D))[q * 2 + 1] = r1;
    }
}

extern "C" void kernel_launch(void* const* d_in, const int* in_sizes, int n_in,
                              void* d_out, int out_size, void* d_ws, size_t ws_size,
                              hipStream_t stream) {
    const float* X  = (const float*)d_in[0];
    const int*   ei = (const int*)d_in[1];   // int32 (JAX canonicalized)
    const float* Wn = (const float*)d_in[2];
    const float* Ws = (const float*)d_in[3];
    const float* b  = (const float*)d_in[4];
    float* out = (float*)d_out;

    int nNodes = in_sizes[0] / D;
    int nEdges = in_sizes[1] / 2;
    const int* src = ei;
    const int* dst = ei + nEdges;

    int n2 = 2 * nNodes;                       // item key space
    int K = (n2 + STEP - 1) / STEP;            // 391 for N=50k
    int WGs = (nEdges + PART_CHUNK - 1) / PART_CHUNK;  // 391
    int nCnt = K * WGs;
    int nb = (nCnt + SCAN_ELEMS - 1) / SCAN_ELEMS;
    int totalItems = 2 * nEdges;

    // workspace (16B-aligned sections, 4B elems):
    // cnt[K*WGs] | scanned[K*WGs] | bsum[256] | off[2N+1] | part[2E u32]
    // | vals[2E u16] | Xh[N*D u16] | hh[N*D u16] | Whn[4096 u16] | Whs[...]
    size_t o = 0;
    auto align4 = [](size_t x) { return (x + 3) & ~(size_t)3; };
    int* cnt     = (int*)d_ws;                 o = align4((size_t)nCnt);
    int* scanned = (int*)d_ws + o;             o = align4(o + (size_t)nCnt);
    int* bsum    = (int*)d_ws + o;             o = align4(o + 256);
    int* off     = (int*)d_ws + o;             o = align4(o + (size_t)n2 + 1);
    unsigned int* part = (unsigned int*)((int*)d_ws + o);
    o = align4(o + 2 * (size_t)nEdges);
    unsigned short* vals = (unsigned short*)((int*)d_ws + o);
    o = align4(o + (size_t)nEdges);            // 2E u16 == E ints
    unsigned short* Xh = (unsigned short*)((int*)d_ws + o);
    o = align4(o + (size_t)nNodes * D / 2);    // N*D u16
    unsigned short* hh = (unsigned short*)((int*)d_ws + o);
    o = align4(o + (size_t)nNodes * D / 2);
    unsigned short* Whn = (unsigned short*)((int*)d_ws + o);
    o = align4(o + (size_t)(D * D) / 2);
    unsigned short* Whs = (unsigned short*)((int*)d_ws + o);

    int n8x = nNodes * D / 8;
    int n8w = D * D / 8;
    int cvtBlocks = (n8x + 2 * n8w + 255) / 256;

    part_hist_cvt<<<WGs + cvtBlocks, 256, 0, stream>>>(
        src, dst, cnt, nEdges, nNodes, K, WGs,
        X, Wn, Ws, Xh, Whn, Whs, n8x, n8w);
    scan_part<<<nb, 256, 0, stream>>>(cnt, bsum, nCnt);
    scan_tops<<<1, 256, 0, stream>>>(bsum, nb);
    scan_final<<<nb, 256, 0, stream>>>(cnt, bsum, scanned, nCnt);
    part_write<<<WGs, 256, 0, stream>>>(src, dst, scanned, part, nEdges, nNodes, K, WGs);
    csr_build<<<K, STEP, 0, stream>>>(part, scanned, vals, off, n2, K, WGs, totalItems);

    int aBlocks = (nNodes + ANODES - 1) / ANODES;
    agg_gemm<<<aBlocks, 512, 0, stream>>>(Xh, off, vals, Whn, Whs, b, hh, nNodes);
    int mBlocks = (nNodes + 7) / 8;
    m_gather<<<mBlocks, 256, 0, stream>>>(hh, off, vals, out, nNodes);
}

// Round 16
// 98.180 us; speedup vs baseline: 1.5939x; 1.0297x over previous
//
#include <hip/hip_runtime.h>
#include <math.h>

#define D 64
#define SCAN_ELEMS 1024    // elements per scan block (256 thr x 4)
#define STEP 256           // nodes per partition bucket (key space 2N)
#define SHIFT 8            // log2(STEP)
#define PART_CHUNK 2048    // edges per partition WG

// Node ids fit u16 (N=50000 < 65536). Partition items: (local_key<<16)|other.
// X, h, W staged bf16. GEMM on MFMA (verified fragment conventions).
// R14/R15: gathers are latency/MLP-bound; 2 node streams/wave. R16: index
// lists are CONTIGUOUS u16 — fetch 32 indices in one coalesced load and
// distribute via __shfl, making all row loads independent & unconditional
// (pad lanes read row 0, masked by cndmask) -> no dependent idx->row chain.

typedef __attribute__((ext_vector_type(8))) short bf16x8;
typedef __attribute__((ext_vector_type(8))) unsigned short u16x8;
typedef __attribute__((ext_vector_type(4))) float f32x4;

__device__ inline unsigned short f2bf(float f) {   // round-to-nearest-even
    unsigned u = __float_as_uint(f);
    return (unsigned short)((u + 0x7FFFu + ((u >> 16) & 1u)) >> 16);
}
__device__ inline float bf2f(unsigned short h) {
    return __uint_as_float(((unsigned)h) << 16);
}

// ---------------------------------------------------------------------------
// part_hist_cvt: blocks [0,WGs) do the per-WG bucket histogram; blocks
// [WGs, WGs+cvtBlocks) convert X/Wn/Ws -> bf16 (independent work, one launch).
// ---------------------------------------------------------------------------
__global__ __launch_bounds__(256) void part_hist_cvt(
    const int* __restrict__ src, const int* __restrict__ dst,
    int* __restrict__ cnt, int nE, int nN, int K, int WGs,
    const float* __restrict__ X, const float* __restrict__ Wn,
    const float* __restrict__ Ws, unsigned short* __restrict__ Xh,
    unsigned short* __restrict__ Whn, unsigned short* __restrict__ Whs,
    int n8x, int n8w) {
    __shared__ int lh[1024];
    int wg = blockIdx.x;
    if (wg >= WGs) {
        int i = (wg - WGs) * 256 + threadIdx.x;
        const float* in; unsigned short* outh; int idx;
        if (i < n8x) { in = X; outh = Xh; idx = i; }
        else if (i < n8x + n8w) { in = Wn; outh = Whn; idx = i - n8x; }
        else if (i < n8x + 2 * n8w) { in = Ws; outh = Whs; idx = i - n8x - n8w; }
        else return;
        const float4* p = (const float4*)in + (size_t)idx * 2;
        float4 a = p[0], b = p[1];
        union { unsigned short us[8]; uint4 v; } u;
        u.us[0] = f2bf(a.x); u.us[1] = f2bf(a.y); u.us[2] = f2bf(a.z); u.us[3] = f2bf(a.w);
        u.us[4] = f2bf(b.x); u.us[5] = f2bf(b.y); u.us[6] = f2bf(b.z); u.us[7] = f2bf(b.w);
        ((uint4*)outh)[idx] = u.v;
        return;
    }
    for (int i = threadIdx.x; i < K; i += 256) lh[i] = 0;
    __syncthreads();
    int base = wg * PART_CHUNK;
    int lim = min(base + PART_CHUNK, nE);
    for (int e = base + threadIdx.x; e < lim; e += 256) {
        int s = src[e], t = dst[e];
        atomicAdd(&lh[t >> SHIFT], 1);
        atomicAdd(&lh[(nN + s) >> SHIFT], 1);
    }
    __syncthreads();
    for (int b = threadIdx.x; b < K; b += 256) cnt[b * WGs + wg] = lh[b];
}

// ---------------------------------------------------------------------------
// scan pass 1: per-block sums
// ---------------------------------------------------------------------------
__global__ __launch_bounds__(256) void scan_part(
    const int* __restrict__ in, int* __restrict__ bsum, int n) {
    __shared__ int sdata[256];
    int b = blockIdx.x, t = threadIdx.x;
    int base = b * SCAN_ELEMS + t * 4;
    int s = 0;
#pragma unroll
    for (int k = 0; k < 4; ++k) { int i = base + k; if (i < n) s += in[i]; }
    sdata[t] = s;
    __syncthreads();
    for (int o = 128; o > 0; o >>= 1) {
        if (t < o) sdata[t] += sdata[t + o];
        __syncthreads();
    }
    if (t == 0) bsum[b] = sdata[0];
}

// ---------------------------------------------------------------------------
// scan pass 2: exclusive scan of block sums in place (nb <= 256)
// ---------------------------------------------------------------------------
__global__ __launch_bounds__(256) void scan_tops(int* __restrict__ bsum, int nb) {
    __shared__ int sd[256];
    int t = threadIdx.x;
    int v = (t < nb) ? bsum[t] : 0;
    sd[t] = v;
    __syncthreads();
    for (int o = 1; o < 256; o <<= 1) {
        int u = (t >= o) ? sd[t - o] : 0;
        __syncthreads();
        sd[t] += u;
        __syncthreads();
    }
    if (t < nb) bsum[t] = sd[t] - v;   // exclusive
}

// ---------------------------------------------------------------------------
// scan pass 3: per-chunk exclusive scan + block offset -> out
// ---------------------------------------------------------------------------
__global__ __launch_bounds__(256) void scan_final(
    const int* __restrict__ in, const int* __restrict__ bsum,
    int* __restrict__ out, int n) {
    __shared__ int sth[256];
    int b = blockIdx.x, t = threadIdx.x;
    int base = b * SCAN_ELEMS + t * 4;
    int v[4]; int s = 0;
#pragma unroll
    for (int k = 0; k < 4; ++k) { int i = base + k; v[k] = (i < n) ? in[i] : 0; s += v[k]; }
    sth[t] = s;
    __syncthreads();
    for (int o = 1; o < 256; o <<= 1) {
        int u = (t >= o) ? sth[t - o] : 0;
        __syncthreads();
        sth[t] += u;
        __syncthreads();
    }
    int run = sth[t] - s + bsum[b];
#pragma unroll
    for (int k = 0; k < 4; ++k) {
        int i = base + k;
        if (i < n) { out[i] = run; run += v[k]; }
    }
}

// ---------------------------------------------------------------------------
// part_write: each WG writes items into ITS OWN contiguous slice of each
// bucket region. Single owner + temporally compact -> writeback ~= payload.
// ---------------------------------------------------------------------------
__global__ __launch_bounds__(256) void part_write(
    const int* __restrict__ src, const int* __restrict__ dst,
    const int* __restrict__ scanned, unsigned int* __restrict__ part,
    int nE, int nN, int K, int WGs) {
    __shared__ int cur[1024];
    int wg = blockIdx.x;
    for (int b = threadIdx.x; b < K; b += 256) cur[b] = scanned[b * WGs + wg];
    __syncthreads();
    int base = wg * PART_CHUNK;
    int lim = min(base + PART_CHUNK, nE);
    for (int e = base + threadIdx.x; e < lim; e += 256) {
        int s = src[e], t = dst[e];
        int k1 = t;
        int p1 = atomicAdd(&cur[k1 >> SHIFT], 1);
        part[p1] = ((unsigned)(k1 & (STEP - 1)) << 16) | (unsigned)s;
        int k2 = nN + s;
        int p2 = atomicAdd(&cur[k2 >> SHIFT], 1);
        part[p2] = ((unsigned)(k2 & (STEP - 1)) << 16) | (unsigned)t;
    }
}

// ---------------------------------------------------------------------------
// csr_build: one WG per bucket. LDS degree count + prefix -> off[] exact,
// then scatter u16 vals into the WG-private region.
// ---------------------------------------------------------------------------
__global__ __launch_bounds__(256) void csr_build(
    const unsigned int* __restrict__ part, const int* __restrict__ scanned,
    unsigned short* __restrict__ vals, int* __restrict__ off,
    int n2, int K, int WGs, int totalItems) {
    __shared__ int deg[STEP];
    __shared__ int pfx[STEP];
    int b = blockIdx.x, t = threadIdx.x;
    int base = scanned[b * WGs];
    int endi = (b + 1 < K) ? scanned[(b + 1) * WGs] : totalItems;

    deg[t] = 0;
    __syncthreads();
    for (int i = base + t; i < endi; i += 256)
        atomicAdd(&deg[part[i] >> 16], 1);
    __syncthreads();

    pfx[t] = deg[t];
    __syncthreads();
    for (int o = 1; o < STEP; o <<= 1) {
        int u = (t >= o) ? pfx[t - o] : 0;
        __syncthreads();
        pfx[t] += u;
        __syncthreads();
    }
    int ex = pfx[t] - deg[t];
    int g = b * STEP + t;
    if (g < n2) off[g] = base + ex;
    if (b == K - 1 && t == 0) off[n2] = totalItems;
    deg[t] = ex;           // reuse as bucket-local cursor
    __syncthreads();

    for (int i = base + t; i < endi; i += 256) {
        unsigned u = part[i];
        int l = (int)(u >> 16);
        int p = atomicAdd(&deg[l], 1);
        vals[base + p] = (unsigned short)(u & 0xffffu);
    }
}

// ---------------------------------------------------------------------------
// Kernel A: 512 thr = 8 waves x 2 node streams = 16 nodes/block. Gather:
// per 32-edge chunk, ONE coalesced u16 index load (32 lanes), indices
// distributed via __shfl; 8 unconditional row loads per group (pad lanes
// read row 0, contribution masked) -> fully pipelined, no idx->row chain.
// Stage 16 bf16 mean-rows + 16 X-rows into 4608B LDS; waves 0-3 compute
// H = relu(Aagg@Wn + Ax@Ws + b) via mfma_f32_16x16x32_bf16 (M fully used).
// ---------------------------------------------------------------------------
#define ANODES 16
#define ROWB 144   // row stride in bytes: 72 u16 (64 data + 8 pad)
__global__ __launch_bounds__(512) void agg_gemm(
    const unsigned short* __restrict__ Xh,    // [N*D] bf16
    const int* __restrict__ off,              // [2N+1]
    const unsigned short* __restrict__ vals,  // [2E]
    const unsigned short* __restrict__ Whn,   // [64*64] bf16
    const unsigned short* __restrict__ Whs,   // [64*64] bf16
    const float* __restrict__ bias,
    unsigned short* __restrict__ hh, int nNodes) {
    __shared__ __align__(16) unsigned short rows[2][16][72];

    int t = threadIdx.x;
    int w = t >> 6;          // wave 0..7
    int lane = t & 63;
    int half = lane >> 5;    // node stream within wave
    int l31 = lane & 31;
    int gg = (lane >> 3) & 3;  // group within stream 0..3
    int q = lane & 7;        // ushort8 chunk: dims 8q..8q+7
    int bb = blockIdx.x * ANODES;
    int node = bb + w * 2 + half;
    bool valid = node < nNodes;

    float acc[8];
#pragma unroll
    for (int j = 0; j < 8; ++j) acc[j] = 0.f;

    int beg = 0, end = 0;
    if (valid) { beg = off[node]; end = off[node + 1]; }
    int deg = end - beg;
    int degO = __shfl_xor(deg, 32);
    int maxDeg = max(deg, degO);   // wave-uniform chunk count

    for (int c = 0; c < maxDeg; c += 32) {
        int idxv = 0;
        if (c + l31 < deg) idxv = vals[beg + c + l31];
        int cnt = deg - c;
#pragma unroll
        for (int u = 0; u < 8; ++u) {
            int e = gg * 8 + u;
            int idx = __shfl(idxv, half * 32 + e);
            u16x8 v = ((const u16x8*)(Xh + (size_t)idx * D))[q];
            float m = (e < cnt) ? 1.0f : 0.0f;
#pragma unroll
            for (int j = 0; j < 8; ++j) acc[j] += m * bf2f(v[j]);
        }
    }
    // reduce across the 4 groups of this stream (lane bits 3,4 only)
#pragma unroll
    for (int j = 0; j < 8; ++j) {
        acc[j] += __shfl_xor(acc[j], 8);
        acc[j] += __shfl_xor(acc[j], 16);
    }

    if (gg == 0) {
        float inv = 1.0f / fmaxf((float)deg, 1.0f);
        u16x8 mv, xv;
        if (valid) {
#pragma unroll
            for (int j = 0; j < 8; ++j) mv[j] = f2bf(acc[j] * inv);
            xv = ((const u16x8*)(Xh + (size_t)node * D))[q];
        } else {
#pragma unroll
            for (int j = 0; j < 8; ++j) { mv[j] = 0; xv[j] = 0; }
        }
        int r = w * 2 + half;
        *(u16x8*)((char*)&rows[0][r][0] + q * 16) = mv;
        *(u16x8*)((char*)&rows[1][r][0] + q * 16) = xv;
    }
    __syncthreads();

    // ---- MFMA: waves 0..3, wave w owns col tile w (cols w*16..+15) -------
    if (w >= 4) return;
    int c = lane & 15;     // A row index / B+C col index
    int hi = lane >> 4;    // k-group / C row-group
    f32x4 accm;
    float bv = bias[w * 16 + c];
    accm[0] = bv; accm[1] = bv; accm[2] = bv; accm[3] = bv;
#pragma unroll
    for (int kh = 0; kh < 2; ++kh) {
        bf16x8 aA = *(const bf16x8*)((const char*)&rows[0][0][0] + c * ROWB + kh * 64 + hi * 16);
        bf16x8 aX = *(const bf16x8*)((const char*)&rows[1][0][0] + c * ROWB + kh * 64 + hi * 16);
        bf16x8 bN, bS;
        int kb = kh * 32 + hi * 8;
#pragma unroll
        for (int j = 0; j < 8; ++j) {
            bN[j] = (short)Whn[(size_t)(kb + j) * D + w * 16 + c];
            bS[j] = (short)Whs[(size_t)(kb + j) * D + w * 16 + c];
        }
        accm = __builtin_amdgcn_mfma_f32_16x16x32_bf16(aA, bN, accm, 0, 0, 0);
        accm = __builtin_amdgcn_mfma_f32_16x16x32_bf16(aX, bS, accm, 0, 0, 0);
    }
    // C/D layout (verified): col = lane&15, row = (lane>>4)*4 + reg
#pragma unroll
    for (int r = 0; r < 4; ++r) {
        int row = hi * 4 + r;
        int n2a = bb + row;
        if (n2a < nNodes)
            hh[(size_t)n2a * D + w * 16 + c] = f2bf(fmaxf(accm[r], 0.0f));
    }
}

// ---------------------------------------------------------------------------
// Kernel B: TWO node streams per wave, shfl-distributed indices (same R16
// structure), 8 unconditional row loads per group per 32-edge chunk.
// Squared diffs vs in-register hn; tanh(mean) -> out. 8 nodes/block.
// ---------------------------------------------------------------------------
__global__ __launch_bounds__(256) void m_gather(
    const unsigned short* __restrict__ hh,    // [N*D] bf16
    const int* __restrict__ off,              // [2N+1], src section at [N..2N]
    const unsigned short* __restrict__ vals,  // [2E]
    float* __restrict__ out, int nNodes) {
    int t = threadIdx.x;
    int w = t >> 6;          // wave 0..3
    int lane = t & 63;
    int half = lane >> 5;    // node stream within wave
    int l31 = lane & 31;
    int gg = (lane >> 3) & 3;  // group within stream 0..3
    int q = lane & 7;        // ushort8 chunk: dims 8q..8q+7
    int node = blockIdx.x * 8 + w * 2 + half;
    bool valid = node < nNodes;

    u16x8 hv = {};
    int beg = 0, end = 0;
    if (valid) {
        hv = ((const u16x8*)(hh + (size_t)node * D))[q];
        beg = off[nNodes + node];
        end = off[nNodes + node + 1];
    }
    float hn[8];
#pragma unroll
    for (int j = 0; j < 8; ++j) hn[j] = bf2f(hv[j]);

    float acc[8];
#pragma unroll
    for (int j = 0; j < 8; ++j) acc[j] = 0.f;

    int deg = end - beg;
    int degO = __shfl_xor(deg, 32);
    int maxDeg = max(deg, degO);   // wave-uniform

    for (int c = 0; c < maxDeg; c += 32) {
        int idxv = 0;
        if (c + l31 < deg) idxv = vals[beg + c + l31];
        int cnt = deg - c;
#pragma unroll
        for (int u = 0; u < 8; ++u) {
            int e = gg * 8 + u;
            int idx = __shfl(idxv, half * 32 + e);
            u16x8 u0 = ((const u16x8*)(hh + (size_t)idx * D))[q];
            float m = (e < cnt) ? 1.0f : 0.0f;
#pragma unroll
            for (int j = 0; j < 8; ++j) {
                float d = hn[j] - bf2f(u0[j]);
                acc[j] += m * d * d;
            }
        }
    }
#pragma unroll
    for (int j = 0; j < 8; ++j) {
        acc[j] += __shfl_xor(acc[j], 8);
        acc[j] += __shfl_xor(acc[j], 16);
    }

    if (valid && gg == 0) {
        float inv = 1.0f / fmaxf((float)deg, 1.0f);
        float4 r0, r1;
        r0.x = tanhf(acc[0] * inv); r0.y = tanhf(acc[1] * inv);
        r0.z = tanhf(acc[2] * inv); r0.w = tanhf(acc[3] * inv);
        r1.x = tanhf(acc[4] * inv); r1.y = tanhf(acc[5] * inv);
        r1.z = tanhf(acc[6] * inv); r1.w = tanhf(acc[7] * inv);
        ((float4*)(out + (size_t)node * D))[q * 2] = r0;
        ((float4*)(out + (size_t)node * D))[q * 2 + 1] = r1;
    }
}

extern "C" void kernel_launch(void* const* d_in, const int* in_sizes, int n_in,
                              void* d_out, int out_size, void* d_ws, size_t ws_size,
                              hipStream_t stream) {
    const float* X  = (const float*)d_in[0];
    const int*   ei = (const int*)d_in[1];   // int32 (JAX canonicalized)
    const float* Wn = (const float*)d_in[2];
    const float* Ws = (const float*)d_in[3];
    const float* b  = (const float*)d_in[4];
    float* out = (float*)d_out;

    int nNodes = in_sizes[0] / D;
    int nEdges = in_sizes[1] / 2;
    const int* src = ei;
    const int* dst = ei + nEdges;

    int n2 = 2 * nNodes;                       // item key space
    int K = (n2 + STEP - 1) / STEP;            // 391 for N=50k
    int WGs = (nEdges + PART_CHUNK - 1) / PART_CHUNK;  // 391
    int nCnt = K * WGs;
    int nb = (nCnt + SCAN_ELEMS - 1) / SCAN_ELEMS;
    int totalItems = 2 * nEdges;

    // workspace (16B-aligned sections, 4B elems):
    // cnt[K*WGs] | scanned[K*WGs] | bsum[256] | off[2N+1] | part[2E u32]
    // | vals[2E u16] | Xh[N*D u16] | hh[N*D u16] | Whn[4096 u16] | Whs[...]
    size_t o = 0;
    auto align4 = [](size_t x) { return (x + 3) & ~(size_t)3; };
    int* cnt     = (int*)d_ws;                 o = align4((size_t)nCnt);
    int* scanned = (int*)d_ws + o;             o = align4(o + (size_t)nCnt);
    int* bsum    = (int*)d_ws + o;             o = align4(o + 256);
    int* off     = (int*)d_ws + o;             o = align4(o + (size_t)n2 + 1);
    unsigned int* part = (unsigned int*)((int*)d_ws + o);
    o = align4(o + 2 * (size_t)nEdges);
    unsigned short* vals = (unsigned short*)((int*)d_ws + o);
    o = align4(o + (size_t)nEdges);            // 2E u16 == E ints
    unsigned short* Xh = (unsigned short*)((int*)d_ws + o);
    o = align4(o + (size_t)nNodes * D / 2);    // N*D u16
    unsigned short* hh = (unsigned short*)((int*)d_ws + o);
    o = align4(o + (size_t)nNodes * D / 2);
    unsigned short* Whn = (unsigned short*)((int*)d_ws + o);
    o = align4(o + (size_t)(D * D) / 2);
    unsigned short* Whs = (unsigned short*)((int*)d_ws + o);

    int n8x = nNodes * D / 8;
    int n8w = D * D / 8;
    int cvtBlocks = (n8x + 2 * n8w + 255) / 256;

    part_hist_cvt<<<WGs + cvtBlocks, 256, 0, stream>>>(
        src, dst, cnt, nEdges, nNodes, K, WGs,
        X, Wn, Ws, Xh, Whn, Whs, n8x, n8w);
    scan_part<<<nb, 256, 0, stream>>>(cnt, bsum, nCnt);
    scan_tops<<<1, 256, 0, stream>>>(bsum, nb);
    scan_final<<<nb, 256, 0, stream>>>(cnt, bsum, scanned, nCnt);
    part_write<<<WGs, 256, 0, stream>>>(src, dst, scanned, part, nEdges, nNodes, K, WGs);
    csr_build<<<K, STEP, 0, stream>>>(part, scanned, vals, off, n2, K, WGs, totalItems);

    int aBlocks = (nNodes + ANODES - 1) / ANODES;
    agg_gemm<<<aBlocks, 512, 0, stream>>>(Xh, off, vals, Whn, Whs, b, hh, nNodes);
    int mBlocks = (nNodes + 7) / 8;
    m_gather<<<mBlocks, 256, 0, stream>>>(hh, off, vals, out, nNodes);
}

// Round 17
// 96.135 us; speedup vs baseline: 1.6278x; 1.0213x over previous
//
#include <hip/hip_runtime.h>
#include <math.h>

#define D 64
#define SCAN_ELEMS 1024    // elements per scan block (256 thr x 4)
#define STEP 256           // nodes per partition bucket (key space 2N)
#define SHIFT 8            // log2(STEP)
#define PART_CHUNK 2048    // edges per partition WG

// Node ids fit u16 (N=50000 < 65536). Partition items: (local_key<<16)|other.
// X, h, W staged bf16. GEMM on MFMA (verified fragment conventions).
// R14-R16: gathers are latency/MLP-bound. R17: FOUR node streams per wave
// (16 lanes each, 2 groups x 8) -> 4 nodes complete per latency period;
// 16-edge chunks fit avg degree 16 with less masking waste.

typedef __attribute__((ext_vector_type(8))) short bf16x8;
typedef __attribute__((ext_vector_type(8))) unsigned short u16x8;
typedef __attribute__((ext_vector_type(4))) float f32x4;

__device__ inline unsigned short f2bf(float f) {   // round-to-nearest-even
    unsigned u = __float_as_uint(f);
    return (unsigned short)((u + 0x7FFFu + ((u >> 16) & 1u)) >> 16);
}
__device__ inline float bf2f(unsigned short h) {
    return __uint_as_float(((unsigned)h) << 16);
}

// ---------------------------------------------------------------------------
// part_hist_cvt: blocks [0,WGs) do the per-WG bucket histogram; blocks
// [WGs, WGs+cvtBlocks) convert X/Wn/Ws -> bf16 (independent work, one launch).
// ---------------------------------------------------------------------------
__global__ __launch_bounds__(256) void part_hist_cvt(
    const int* __restrict__ src, const int* __restrict__ dst,
    int* __restrict__ cnt, int nE, int nN, int K, int WGs,
    const float* __restrict__ X, const float* __restrict__ Wn,
    const float* __restrict__ Ws, unsigned short* __restrict__ Xh,
    unsigned short* __restrict__ Whn, unsigned short* __restrict__ Whs,
    int n8x, int n8w) {
    __shared__ int lh[1024];
    int wg = blockIdx.x;
    if (wg >= WGs) {
        int i = (wg - WGs) * 256 + threadIdx.x;
        const float* in; unsigned short* outh; int idx;
        if (i < n8x) { in = X; outh = Xh; idx = i; }
        else if (i < n8x + n8w) { in = Wn; outh = Whn; idx = i - n8x; }
        else if (i < n8x + 2 * n8w) { in = Ws; outh = Whs; idx = i - n8x - n8w; }
        else return;
        const float4* p = (const float4*)in + (size_t)idx * 2;
        float4 a = p[0], b = p[1];
        union { unsigned short us[8]; uint4 v; } u;
        u.us[0] = f2bf(a.x); u.us[1] = f2bf(a.y); u.us[2] = f2bf(a.z); u.us[3] = f2bf(a.w);
        u.us[4] = f2bf(b.x); u.us[5] = f2bf(b.y); u.us[6] = f2bf(b.z); u.us[7] = f2bf(b.w);
        ((uint4*)outh)[idx] = u.v;
        return;
    }
    for (int i = threadIdx.x; i < K; i += 256) lh[i] = 0;
    __syncthreads();
    int base = wg * PART_CHUNK;
    int lim = min(base + PART_CHUNK, nE);
    for (int e = base + threadIdx.x; e < lim; e += 256) {
        int s = src[e], t = dst[e];
        atomicAdd(&lh[t >> SHIFT], 1);
        atomicAdd(&lh[(nN + s) >> SHIFT], 1);
    }
    __syncthreads();
    for (int b = threadIdx.x; b < K; b += 256) cnt[b * WGs + wg] = lh[b];
}

// ---------------------------------------------------------------------------
// scan pass 1: per-block sums
// ---------------------------------------------------------------------------
__global__ __launch_bounds__(256) void scan_part(
    const int* __restrict__ in, int* __restrict__ bsum, int n) {
    __shared__ int sdata[256];
    int b = blockIdx.x, t = threadIdx.x;
    int base = b * SCAN_ELEMS + t * 4;
    int s = 0;
#pragma unroll
    for (int k = 0; k < 4; ++k) { int i = base + k; if (i < n) s += in[i]; }
    sdata[t] = s;
    __syncthreads();
    for (int o = 128; o > 0; o >>= 1) {
        if (t < o) sdata[t] += sdata[t + o];
        __syncthreads();
    }
    if (t == 0) bsum[b] = sdata[0];
}

// ---------------------------------------------------------------------------
// scan pass 2: exclusive scan of block sums in place (nb <= 256)
// ---------------------------------------------------------------------------
__global__ __launch_bounds__(256) void scan_tops(int* __restrict__ bsum, int nb) {
    __shared__ int sd[256];
    int t = threadIdx.x;
    int v = (t < nb) ? bsum[t] : 0;
    sd[t] = v;
    __syncthreads();
    for (int o = 1; o < 256; o <<= 1) {
        int u = (t >= o) ? sd[t - o] : 0;
        __syncthreads();
        sd[t] += u;
        __syncthreads();
    }
    if (t < nb) bsum[t] = sd[t] - v;   // exclusive
}

// ---------------------------------------------------------------------------
// scan pass 3: per-chunk exclusive scan + block offset -> out
// ---------------------------------------------------------------------------
__global__ __launch_bounds__(256) void scan_final(
    const int* __restrict__ in, const int* __restrict__ bsum,
    int* __restrict__ out, int n) {
    __shared__ int sth[256];
    int b = blockIdx.x, t = threadIdx.x;
    int base = b * SCAN_ELEMS + t * 4;
    int v[4]; int s = 0;
#pragma unroll
    for (int k = 0; k < 4; ++k) { int i = base + k; v[k] = (i < n) ? in[i] : 0; s += v[k]; }
    sth[t] = s;
    __syncthreads();
    for (int o = 1; o < 256; o <<= 1) {
        int u = (t >= o) ? sth[t - o] : 0;
        __syncthreads();
        sth[t] += u;
        __syncthreads();
    }
    int run = sth[t] - s + bsum[b];
#pragma unroll
    for (int k = 0; k < 4; ++k) {
        int i = base + k;
        if (i < n) { out[i] = run; run += v[k]; }
    }
}

// ---------------------------------------------------------------------------
// part_write: each WG writes items into ITS OWN contiguous slice of each
// bucket region. Single owner + temporally compact -> writeback ~= payload.
// ---------------------------------------------------------------------------
__global__ __launch_bounds__(256) void part_write(
    const int* __restrict__ src, const int* __restrict__ dst,
    const int* __restrict__ scanned, unsigned int* __restrict__ part,
    int nE, int nN, int K, int WGs) {
    __shared__ int cur[1024];
    int wg = blockIdx.x;
    for (int b = threadIdx.x; b < K; b += 256) cur[b] = scanned[b * WGs + wg];
    __syncthreads();
    int base = wg * PART_CHUNK;
    int lim = min(base + PART_CHUNK, nE);
    for (int e = base + threadIdx.x; e < lim; e += 256) {
        int s = src[e], t = dst[e];
        int k1 = t;
        int p1 = atomicAdd(&cur[k1 >> SHIFT], 1);
        part[p1] = ((unsigned)(k1 & (STEP - 1)) << 16) | (unsigned)s;
        int k2 = nN + s;
        int p2 = atomicAdd(&cur[k2 >> SHIFT], 1);
        part[p2] = ((unsigned)(k2 & (STEP - 1)) << 16) | (unsigned)t;
    }
}

// ---------------------------------------------------------------------------
// csr_build: one WG per bucket. LDS degree count + prefix -> off[] exact,
// then scatter u16 vals into the WG-private region.
// ---------------------------------------------------------------------------
__global__ __launch_bounds__(256) void csr_build(
    const unsigned int* __restrict__ part, const int* __restrict__ scanned,
    unsigned short* __restrict__ vals, int* __restrict__ off,
    int n2, int K, int WGs, int totalItems) {
    __shared__ int deg[STEP];
    __shared__ int pfx[STEP];
    int b = blockIdx.x, t = threadIdx.x;
    int base = scanned[b * WGs];
    int endi = (b + 1 < K) ? scanned[(b + 1) * WGs] : totalItems;

    deg[t] = 0;
    __syncthreads();
    for (int i = base + t; i < endi; i += 256)
        atomicAdd(&deg[part[i] >> 16], 1);
    __syncthreads();

    pfx[t] = deg[t];
    __syncthreads();
    for (int o = 1; o < STEP; o <<= 1) {
        int u = (t >= o) ? pfx[t - o] : 0;
        __syncthreads();
        pfx[t] += u;
        __syncthreads();
    }
    int ex = pfx[t] - deg[t];
    int g = b * STEP + t;
    if (g < n2) off[g] = base + ex;
    if (b == K - 1 && t == 0) off[n2] = totalItems;
    deg[t] = ex;           // reuse as bucket-local cursor
    __syncthreads();

    for (int i = base + t; i < endi; i += 256) {
        unsigned u = part[i];
        int l = (int)(u >> 16);
        int p = atomicAdd(&deg[l], 1);
        vals[base + p] = (unsigned short)(u & 0xffffu);
    }
}

// ---------------------------------------------------------------------------
// Kernel A: 512 thr = 8 waves x 4 node streams = 32 nodes/block. Gather:
// per stream 16 lanes (2 groups x 8), 16-edge chunks, one coalesced u16
// index load + __shfl distribution, 8 unconditional row loads per group
// (pad -> row 0, masked). Reduce xor(8). Stage 32 bf16 mean-rows + 32
// X-rows into 9216B LDS; 8 waves run two 16-row MFMA blocks
// (wave w: rows (w>>2)*16.., col tile (w&3)) via mfma_f32_16x16x32_bf16.
// ---------------------------------------------------------------------------
#define ANODES 32
#define ROWB 144   // row stride in bytes: 72 u16 (64 data + 8 pad)
__global__ __launch_bounds__(512) void agg_gemm(
    const unsigned short* __restrict__ Xh,    // [N*D] bf16
    const int* __restrict__ off,              // [2N+1]
    const unsigned short* __restrict__ vals,  // [2E]
    const unsigned short* __restrict__ Whn,   // [64*64] bf16
    const unsigned short* __restrict__ Whs,   // [64*64] bf16
    const float* __restrict__ bias,
    unsigned short* __restrict__ hh, int nNodes) {
    __shared__ __align__(16) unsigned short rows[2][32][72];

    int t = threadIdx.x;
    int w = t >> 6;            // wave 0..7
    int lane = t & 63;
    int st = (lane >> 4) & 3;  // node stream 0..3
    int l15 = lane & 15;
    int grp = (lane >> 3) & 1; // group within stream
    int q = lane & 7;          // ushort8 chunk: dims 8q..8q+7
    int bb = blockIdx.x * ANODES;
    int node = bb + w * 4 + st;
    bool valid = node < nNodes;

    float acc[8];
#pragma unroll
    for (int j = 0; j < 8; ++j) acc[j] = 0.f;

    int beg = 0, deg = 0;
    if (valid) { beg = off[node]; deg = off[node + 1] - beg; }
    int chunks = (deg + 15) >> 4;
    int m1 = max(chunks, __shfl_xor(chunks, 16));
    int maxChunks = max(m1, __shfl_xor(m1, 32));   // wave-uniform

    for (int cc = 0; cc < maxChunks; ++cc) {
        int c = cc * 16;
        int idxv = 0;
        if (c + l15 < deg) idxv = vals[beg + c + l15];
        int cnt = deg - c;
#pragma unroll
        for (int u = 0; u < 8; ++u) {
            int e = grp * 8 + u;
            int idx = __shfl(idxv, st * 16 + e);
            u16x8 v = ((const u16x8*)(Xh + (size_t)idx * D))[q];
            float m = (e < cnt) ? 1.0f : 0.0f;
#pragma unroll
            for (int j = 0; j < 8; ++j) acc[j] += m * bf2f(v[j]);
        }
    }
    // reduce across the 2 groups of this stream (lane bit 3)
#pragma unroll
    for (int j = 0; j < 8; ++j) acc[j] += __shfl_xor(acc[j], 8);

    if (grp == 0) {
        float inv = 1.0f / fmaxf((float)deg, 1.0f);
        u16x8 mv, xv;
        if (valid) {
#pragma unroll
            for (int j = 0; j < 8; ++j) mv[j] = f2bf(acc[j] * inv);
            xv = ((const u16x8*)(Xh + (size_t)node * D))[q];
        } else {
#pragma unroll
            for (int j = 0; j < 8; ++j) { mv[j] = 0; xv[j] = 0; }
        }
        int r = w * 4 + st;
        *(u16x8*)((char*)&rows[0][r][0] + q * 16) = mv;
        *(u16x8*)((char*)&rows[1][r][0] + q * 16) = xv;
    }
    __syncthreads();

    // ---- MFMA: wave w -> row block rb = w>>2 (16 rows), col tile ct = w&3
    int rb = w >> 2;
    int ct = w & 3;
    int c = lane & 15;     // A row within block / B+C col
    int hi = lane >> 4;    // k-group / C row-group
    f32x4 accm;
    float bv = bias[ct * 16 + c];
    accm[0] = bv; accm[1] = bv; accm[2] = bv; accm[3] = bv;
#pragma unroll
    for (int kh = 0; kh < 2; ++kh) {
        bf16x8 aA = *(const bf16x8*)((const char*)&rows[0][0][0] + (rb * 16 + c) * ROWB + kh * 64 + hi * 16);
        bf16x8 aX = *(const bf16x8*)((const char*)&rows[1][0][0] + (rb * 16 + c) * ROWB + kh * 64 + hi * 16);
        bf16x8 bN, bS;
        int kb = kh * 32 + hi * 8;
#pragma unroll
        for (int j = 0; j < 8; ++j) {
            bN[j] = (short)Whn[(size_t)(kb + j) * D + ct * 16 + c];
            bS[j] = (short)Whs[(size_t)(kb + j) * D + ct * 16 + c];
        }
        accm = __builtin_amdgcn_mfma_f32_16x16x32_bf16(aA, bN, accm, 0, 0, 0);
        accm = __builtin_amdgcn_mfma_f32_16x16x32_bf16(aX, bS, accm, 0, 0, 0);
    }
    // C/D layout (verified): col = lane&15, row = (lane>>4)*4 + reg
#pragma unroll
    for (int r = 0; r < 4; ++r) {
        int row = hi * 4 + r;
        int n2a = bb + rb * 16 + row;
        if (n2a < nNodes)
            hh[(size_t)n2a * D + ct * 16 + c] = f2bf(fmaxf(accm[r], 0.0f));
    }
}

// ---------------------------------------------------------------------------
// Kernel B: 4 node streams per wave (16 lanes each), 16-edge chunks,
// shfl-distributed indices, 8 unconditional row loads per group.
// 16 nodes/block. Squared diffs vs in-register hn; tanh(mean) -> out.
// ---------------------------------------------------------------------------
__global__ __launch_bounds__(256) void m_gather(
    const unsigned short* __restrict__ hh,    // [N*D] bf16
    const int* __restrict__ off,              // [2N+1], src section at [N..2N]
    const unsigned short* __restrict__ vals,  // [2E]
    float* __restrict__ out, int nNodes) {
    int t = threadIdx.x;
    int w = t >> 6;            // wave 0..3
    int lane = t & 63;
    int st = (lane >> 4) & 3;  // node stream 0..3
    int l15 = lane & 15;
    int grp = (lane >> 3) & 1;
    int q = lane & 7;          // ushort8 chunk: dims 8q..8q+7
    int node = blockIdx.x * 16 + w * 4 + st;
    bool valid = node < nNodes;

    u16x8 hv = {};
    int beg = 0, deg = 0;
    if (valid) {
        hv = ((const u16x8*)(hh + (size_t)node * D))[q];
        beg = off[nNodes + node];
        deg = off[nNodes + node + 1] - beg;
    }
    float hn[8];
#pragma unroll
    for (int j = 0; j < 8; ++j) hn[j] = bf2f(hv[j]);

    float acc[8];
#pragma unroll
    for (int j = 0; j < 8; ++j) acc[j] = 0.f;

    int chunks = (deg + 15) >> 4;
    int m1 = max(chunks, __shfl_xor(chunks, 16));
    int maxChunks = max(m1, __shfl_xor(m1, 32));   // wave-uniform

    for (int cc = 0; cc < maxChunks; ++cc) {
        int c = cc * 16;
        int idxv = 0;
        if (c + l15 < deg) idxv = vals[beg + c + l15];
        int cnt = deg - c;
#pragma unroll
        for (int u = 0; u < 8; ++u) {
            int e = grp * 8 + u;
            int idx = __shfl(idxv, st * 16 + e);
            u16x8 u0 = ((const u16x8*)(hh + (size_t)idx * D))[q];
            float m = (e < cnt) ? 1.0f : 0.0f;
#pragma unroll
            for (int j = 0; j < 8; ++j) {
                float d = hn[j] - bf2f(u0[j]);
                acc[j] += m * d * d;
            }
        }
    }
#pragma unroll
    for (int j = 0; j < 8; ++j) acc[j] += __shfl_xor(acc[j], 8);

    if (valid && grp == 0) {
        float inv = 1.0f / fmaxf((float)deg, 1.0f);
        float4 r0, r1;
        r0.x = tanhf(acc[0] * inv); r0.y = tanhf(acc[1] * inv);
        r0.z = tanhf(acc[2] * inv); r0.w = tanhf(acc[3] * inv);
        r1.x = tanhf(acc[4] * inv); r1.y = tanhf(acc[5] * inv);
        r1.z = tanhf(acc[6] * inv); r1.w = tanhf(acc[7] * inv);
        ((float4*)(out + (size_t)node * D))[q * 2] = r0;
        ((float4*)(out + (size_t)node * D))[q * 2 + 1] = r1;
    }
}

extern "C" void kernel_launch(void* const* d_in, const int* in_sizes, int n_in,
                              void* d_out, int out_size, void* d_ws, size_t ws_size,
                              hipStream_t stream) {
    const float* X  = (const float*)d_in[0];
    const int*   ei = (const int*)d_in[1];   // int32 (JAX canonicalized)
    const float* Wn = (const float*)d_in[2];
    const float* Ws = (const float*)d_in[3];
    const float* b  = (const float*)d_in[4];
    float* out = (float*)d_out;

    int nNodes = in_sizes[0] / D;
    int nEdges = in_sizes[1] / 2;
    const int* src = ei;
    const int* dst = ei + nEdges;

    int n2 = 2 * nNodes;                       // item key space
    int K = (n2 + STEP - 1) / STEP;            // 391 for N=50k
    int WGs = (nEdges + PART_CHUNK - 1) / PART_CHUNK;  // 391
    int nCnt = K * WGs;
    int nb = (nCnt + SCAN_ELEMS - 1) / SCAN_ELEMS;
    int totalItems = 2 * nEdges;

    // workspace (16B-aligned sections, 4B elems):
    // cnt[K*WGs] | scanned[K*WGs] | bsum[256] | off[2N+1] | part[2E u32]
    // | vals[2E u16] | Xh[N*D u16] | hh[N*D u16] | Whn[4096 u16] | Whs[...]
    size_t o = 0;
    auto align4 = [](size_t x) { return (x + 3) & ~(size_t)3; };
    int* cnt     = (int*)d_ws;                 o = align4((size_t)nCnt);
    int* scanned = (int*)d_ws + o;             o = align4(o + (size_t)nCnt);
    int* bsum    = (int*)d_ws + o;             o = align4(o + 256);
    int* off     = (int*)d_ws + o;             o = align4(o + (size_t)n2 + 1);
    unsigned int* part = (unsigned int*)((int*)d_ws + o);
    o = align4(o + 2 * (size_t)nEdges);
    unsigned short* vals = (unsigned short*)((int*)d_ws + o);
    o = align4(o + (size_t)nEdges);            // 2E u16 == E ints
    unsigned short* Xh = (unsigned short*)((int*)d_ws + o);
    o = align4(o + (size_t)nNodes * D / 2);    // N*D u16
    unsigned short* hh = (unsigned short*)((int*)d_ws + o);
    o = align4(o + (size_t)nNodes * D / 2);
    unsigned short* Whn = (unsigned short*)((int*)d_ws + o);
    o = align4(o + (size_t)(D * D) / 2);
    unsigned short* Whs = (unsigned short*)((int*)d_ws + o);

    int n8x = nNodes * D / 8;
    int n8w = D * D / 8;
    int cvtBlocks = (n8x + 2 * n8w + 255) / 256;

    part_hist_cvt<<<WGs + cvtBlocks, 256, 0, stream>>>(
        src, dst, cnt, nEdges, nNodes, K, WGs,
        X, Wn, Ws, Xh, Whn, Whs, n8x, n8w);
    scan_part<<<nb, 256, 0, stream>>>(cnt, bsum, nCnt);
    scan_tops<<<1, 256, 0, stream>>>(bsum, nb);
    scan_final<<<nb, 256, 0, stream>>>(cnt, bsum, scanned, nCnt);
    part_write<<<WGs, 256, 0, stream>>>(src, dst, scanned, part, nEdges, nNodes, K, WGs);
    csr_build<<<K, STEP, 0, stream>>>(part, scanned, vals, off, n2, K, WGs, totalItems);

    int aBlocks = (nNodes + ANODES - 1) / ANODES;
    agg_gemm<<<aBlocks, 512, 0, stream>>>(Xh, off, vals, Whn, Whs, b, hh, nNodes);
    int mBlocks = (nNodes + 15) / 16;
    m_gather<<<mBlocks, 256, 0, stream>>>(hh, off, vals, out, nNodes);
}